// Round 7
// baseline (1926.553 us; speedup 1.0000x reference)
//
#include <hip/hip_runtime.h>
#include <math.h>

#define NTOK 200704          // B*S = 4096*49
#define CDIM 384
#define NH3  1152            // 3*C
#define NHEADS 12
#define HD   32
#define SEQ  49
#define QL   77070336ULL     // CDIM*NTOK (one third of T)
#define MPAD 1280            // padded M for gemm1 (1152 -> 5*256)

typedef __attribute__((ext_vector_type(8))) short short8;
typedef __attribute__((ext_vector_type(4))) float f32x4;

__device__ __forceinline__ float gelu_exact(float x) {
    return 0.5f * x * (1.0f + erff(x * 0.70710678118654752f));
}
__device__ __forceinline__ unsigned bf16rn_bits(float x) {
    unsigned u = __float_as_uint(x);
    return (u + 0x7fffu + ((u >> 16) & 1u)) & 0xffff0000u;
}
__device__ __forceinline__ unsigned packsplit(float x) {
    unsigned hb = bf16rn_bits(x);
    float r = x - __uint_as_float(hb);
    unsigned lb = bf16rn_bits(r);
    return hb | (lb >> 16);
}
__device__ __forceinline__ void gl_lds16(const void* g, void* l) {
    __builtin_amdgcn_global_load_lds((const __attribute__((address_space(1))) void*)g,
                                     (__attribute__((address_space(3))) void*)l, 16, 0, 0);
}
union F8 { short8 v; unsigned u[4]; };
__device__ __forceinline__ void unpack8(uint4 a, uint4 b, short8 &h, short8 &l) {
    F8 H, L;
    H.u[0] = __builtin_amdgcn_perm(a.y, a.x, 0x07060302u);
    H.u[1] = __builtin_amdgcn_perm(a.w, a.z, 0x07060302u);
    H.u[2] = __builtin_amdgcn_perm(b.y, b.x, 0x07060302u);
    H.u[3] = __builtin_amdgcn_perm(b.w, b.z, 0x07060302u);
    L.u[0] = __builtin_amdgcn_perm(a.y, a.x, 0x05040100u);
    L.u[1] = __builtin_amdgcn_perm(a.w, a.z, 0x05040100u);
    L.u[2] = __builtin_amdgcn_perm(b.y, b.x, 0x05040100u);
    L.u[3] = __builtin_amdgcn_perm(b.w, b.z, 0x05040100u);
    h = H.v; l = L.v;
}

// ---------------------------------------------------------------------------
// prep_w: w (Kdim x Msrc row-major fp32) -> hi/lo bf16 granules [koct][Mstore][8]
// rows >= Msrc are zero-padded.
// ---------------------------------------------------------------------------
__global__ __launch_bounds__(256)
void prep_w(const float* __restrict__ w, unsigned short* __restrict__ hi,
            unsigned short* __restrict__ lo, int Msrc, int Mstore, int Kdim) {
    int idx = blockIdx.x * 256 + threadIdx.x;
    int total = Mstore * (Kdim >> 3);
    if (idx >= total) return;
    int koct = idx / Mstore, m = idx - koct * Mstore;
    unsigned short h8[8], l8[8];
    #pragma unroll
    for (int j = 0; j < 8; ++j) {
        float v = (m < Msrc) ? w[(size_t)(koct * 8 + j) * Msrc + m] : 0.f;
        unsigned hb = bf16rn_bits(v);
        h8[j] = (unsigned short)(hb >> 16);
        l8[j] = (unsigned short)(bf16rn_bits(v - __uint_as_float(hb)) >> 16);
    }
    size_t o = (size_t)idx * 8;
    *(short8*)&hi[o] = *(short8*)h8;
    *(short8*)&lo[o] = *(short8*)l8;
}

// prep_x: fp32 row-major -> packed-split u32, same layout
__global__ __launch_bounds__(256)
void prep_x(const float* __restrict__ x, unsigned* __restrict__ xp, int total8) {
    int idx = blockIdx.x * 256 + threadIdx.x;
    if (idx >= total8) return;
    size_t e = (size_t)idx * 8;
    float4 v0 = *(const float4*)&x[e];
    float4 v1 = *(const float4*)&x[e + 4];
    *(uint4*)&xp[e]     = make_uint4(packsplit(v0.x), packsplit(v0.y), packsplit(v0.z), packsplit(v0.w));
    *(uint4*)&xp[e + 4] = make_uint4(packsplit(v1.x), packsplit(v1.y), packsplit(v1.z), packsplit(v1.w));
}

// ---------------------------------------------------------------------------
// gemm8p: 256x256 tile, 8 waves (2M x 4N, wave 128x64), BK=32 packed-k,
// double-buffered 128 KB LDS, counted-vmcnt pipeline (never 0 in loop),
// raw s_barrier, setprio around MFMA clusters. bf16x3.
// A = weight granules [koct][MPAD][8] hi/lo u16; B = packed u32 [NTOK][K].
// out packed u32, gelu+bias epilogue.
// ---------------------------------------------------------------------------
__global__ __launch_bounds__(512, 2)
void gemm8p(const unsigned short* __restrict__ Agh, const unsigned short* __restrict__ Agl,
            const unsigned* __restrict__ Bp,
            const float* __restrict__ bias, unsigned* __restrict__ outP,
            int N, int K, int Mreal) {
    // per buffer: Ah 16K | Al 16K | B 32K  => 64K; two buffers = 128K
    __shared__ char lds[131072] __attribute__((aligned(16)));

    const int tid = threadIdx.x;
    const int wg = (blockIdx.x & 7) * 490 + (blockIdx.x >> 3);  // 3920 = 8*490
    const int mT = wg % 5, nT = wg / 5;                          // M-fast: share token tile
    const int m0 = mT * 256, n0 = nT * 256;

    const int wid = tid >> 6, lane = tid & 63;
    const int wm = wid >> 2, wn = wid & 3;     // 2 x 4 wave grid
    const int r15 = lane & 15, q = lane >> 4;

    f32x4 acc[8][4] = {};
    const int nK = K / 32;                     // 12

    auto stage = [&](int kt, int buf) {
        char* base = lds + buf * 65536;
        const int kb = kt * 4;                 // koct base
        // A granules: 1024 units of 16B (hi) + 1024 (lo)
        #pragma unroll
        for (int it = 0; it < 2; ++it) {
            int g = it * 512 + tid;            // 0..1023
            int koct = g >> 8, r = g & 255;
            size_t src = ((size_t)(kb + koct) * MPAD + m0 + r) * 8;
            gl_lds16(Agh + src, base + g * 16);
            gl_lds16(Agl + src, base + 16384 + g * 16);
        }
        // B packed: 256 rows x 128B, XOR slot swizzle
        #pragma unroll
        for (int it = 0; it < 4; ++it) {
            int row = it * 64 + (tid >> 3);
            int slot = (tid & 7) ^ (row & 7);
            gl_lds16(Bp + (size_t)(n0 + row) * K + kt * 32 + slot * 4,
                     base + 32768 + (it * 512 + tid) * 16);
        }
    };

    auto compute = [&](int buf) {
        const char* base = lds + buf * 65536;
        const char* aHi = base;
        const char* aLo = base + 16384;
        const char* bB  = base + 32768;
        // B fragments (4 pairs) once
        short8 bh[4], bl[4];
        #pragma unroll
        for (int ni = 0; ni < 4; ++ni) {
            int r = wn * 64 + ni * 16 + r15;
            int s0 = (2 * q) ^ (r & 7);
            const char* p = bB + r * 128;
            uint4 ua = *(const uint4*)(p + s0 * 16);
            uint4 ub = *(const uint4*)(p + (s0 ^ 1) * 16);
            unpack8(ua, ub, bh[ni], bl[ni]);
        }
        // 4 phases of 2 m-subtiles each
        #pragma unroll
        for (int p = 0; p < 4; ++p) {
            short8 ah[2], al[2];
            #pragma unroll
            for (int u = 0; u < 2; ++u) {
                int mi = p * 2 + u;
                int r = wm * 128 + mi * 16 + r15;
                ah[u] = *(const short8*)(aHi + (q * 256 + r) * 16);
                al[u] = *(const short8*)(aLo + (q * 256 + r) * 16);
            }
            __builtin_amdgcn_s_setprio(1);
            #pragma unroll
            for (int u = 0; u < 2; ++u) {
                int mi = p * 2 + u;
                #pragma unroll
                for (int ni = 0; ni < 4; ++ni) {
                    acc[mi][ni] = __builtin_amdgcn_mfma_f32_16x16x32_bf16(ah[u], bh[ni], acc[mi][ni], 0, 0, 0);
                    acc[mi][ni] = __builtin_amdgcn_mfma_f32_16x16x32_bf16(ah[u], bl[ni], acc[mi][ni], 0, 0, 0);
                    acc[mi][ni] = __builtin_amdgcn_mfma_f32_16x16x32_bf16(al[u], bh[ni], acc[mi][ni], 0, 0, 0);
                }
            }
            __builtin_amdgcn_s_setprio(0);
        }
    };

    // prologue: fill both buffers, wait for tile 0 only
    stage(0, 0);
    stage(1, 1);
    asm volatile("s_waitcnt vmcnt(8)" ::: "memory");
    __builtin_amdgcn_sched_barrier(0);
    __builtin_amdgcn_s_barrier();

    for (int kt = 0; kt < nK; ++kt) {
        compute(kt & 1);
        asm volatile("s_waitcnt lgkmcnt(0)" ::: "memory");
        __builtin_amdgcn_s_barrier();
        __builtin_amdgcn_sched_barrier(0);
        if (kt + 2 < nK) stage(kt + 2, kt & 1);
        if (kt + 1 < nK) {
            if (kt + 2 < nK) asm volatile("s_waitcnt vmcnt(8)" ::: "memory");
            else             asm volatile("s_waitcnt vmcnt(0)" ::: "memory");
            __builtin_amdgcn_sched_barrier(0);
            __builtin_amdgcn_s_barrier();
        }
    }

    // epilogue: gelu(acc + bias) -> packed u32, guard padded rows
    #pragma unroll
    for (int mi = 0; mi < 8; ++mi) {
        int gr0 = m0 + wm * 128 + mi * 16 + q * 4;
        #pragma unroll
        for (int ni = 0; ni < 4; ++ni) {
            int gc = n0 + wn * 64 + ni * 16 + r15;
            #pragma unroll
            for (int j = 0; j < 4; ++j) {
                int gr = gr0 + j;
                if (gr < Mreal) {
                    float v = gelu_exact(acc[mi][ni][j] + bias[gr]);
                    outP[(size_t)gr * N + gc] = packsplit(v);
                }
            }
        }
    }
}

// ---------------------------------------------------------------------------
// R4-proven single-buffered 128x128 bf16x3 GEMM (gemm3/4 + fallback).
// ---------------------------------------------------------------------------
template<int AMODE, int BMODE, bool BIAS_ROW, bool OUTF>
__global__ __launch_bounds__(256, 2)
void gemm_b3(const float* __restrict__ Af,
             const unsigned short* __restrict__ Agh, const unsigned short* __restrict__ Agl,
             const unsigned* __restrict__ Ap,
             const float* __restrict__ Bf,
             const unsigned short* __restrict__ Bgh, const unsigned short* __restrict__ Bgl,
             const unsigned* __restrict__ Bp,
             const float* __restrict__ bias, float* __restrict__ outF,
             unsigned* __restrict__ outP,
             int M, int N, int K, int nMt, int cpx) {
    __shared__ char smA[16384];
    __shared__ char smB[16384];
    const int tid = threadIdx.x;
    int m0, n0;
    if (cpx > 0) {
        int wg = (blockIdx.x & 7) * cpx + (blockIdx.x >> 3);
        m0 = (wg % nMt) * 128;
        n0 = (wg / nMt) * 128;
    } else {
        n0 = blockIdx.x * 128;
        m0 = blockIdx.y * 128;
    }
    const int wid = tid >> 6, lane = tid & 63;
    const int wm = wid >> 1, wn = wid & 1;
    const int r15 = lane & 15, q = lane >> 4;
    const int f_r = tid >> 3, f_f4 = tid & 7;
    const int f_qq = f_f4 >> 1, f_half = (f_f4 & 1) * 8;

    unsigned short* BhT = (unsigned short*)smB;
    unsigned short* BlT = (unsigned short*)(smB + 8192);

    f32x4 acc[4][4] = {};

    for (int k0 = 0; k0 < K; k0 += 32) {
        const int kb = k0 >> 3;
        if constexpr (AMODE == 1) {
            #pragma unroll
            for (int it = 0; it < 2; ++it) {
                int g = it * 256 + tid;
                int qq = g >> 7, r = g & 127;
                size_t src = ((size_t)(kb + qq) * M + m0 + r) * 8;
                gl_lds16(Agh + src, smA + g * 16);
                gl_lds16(Agl + src, smA + 8192 + g * 16);
            }
        } else if constexpr (AMODE == 2) {
            #pragma unroll
            for (int it = 0; it < 4; ++it) {
                int row = it * 32 + (tid >> 3);
                int slot = (tid & 7) ^ (row & 7);
                gl_lds16(Ap + (size_t)(m0 + row) * K + k0 + slot * 4,
                         smA + (size_t)(it * 256 + tid) * 16);
            }
        }
        if constexpr (BMODE == 1) {
            #pragma unroll
            for (int it = 0; it < 2; ++it) {
                int g = it * 256 + tid;
                int qq = g >> 7, r = g & 127;
                size_t src = ((size_t)(kb + qq) * N + n0 + r) * 8;
                gl_lds16(Bgh + src, smB + g * 16);
                gl_lds16(Bgl + src, smB + 8192 + g * 16);
            }
        } else if constexpr (BMODE == 2) {
            #pragma unroll
            for (int it = 0; it < 4; ++it) {
                int row = it * 32 + (tid >> 3);
                int slot = (tid & 7) ^ (row & 7);
                gl_lds16(Bp + (size_t)(n0 + row) * K + k0 + slot * 4,
                         smB + (size_t)(it * 256 + tid) * 16);
            }
        } else {
            #pragma unroll
            for (int it = 0; it < 4; ++it) {
                int r = it * 32 + f_r;
                float4 v = *(const float4*)&Bf[(size_t)(n0 + r) * K + k0 + f_f4 * 4];
                unsigned hb0 = bf16rn_bits(v.x), hb1 = bf16rn_bits(v.y);
                unsigned hb2 = bf16rn_bits(v.z), hb3 = bf16rn_bits(v.w);
                unsigned l0 = bf16rn_bits(v.x - __uint_as_float(hb0)) >> 16;
                unsigned l1 = bf16rn_bits(v.y - __uint_as_float(hb1)) >> 16;
                unsigned l2 = bf16rn_bits(v.z - __uint_as_float(hb2)) >> 16;
                unsigned l3 = bf16rn_bits(v.w - __uint_as_float(hb3)) >> 16;
                unsigned h0 = hb0 >> 16, h1 = hb1 >> 16, h2 = hb2 >> 16, h3 = hb3 >> 16;
                *(uint2*)((char*)(BhT + (f_qq * 128 + r) * 8) + f_half) =
                    make_uint2(h0 | (h1 << 16), h2 | (h3 << 16));
                *(uint2*)((char*)(BlT + (f_qq * 128 + r) * 8) + f_half) =
                    make_uint2(l0 | (l1 << 16), l2 | (l3 << 16));
            }
        }
        __syncthreads();

        short8 ah[4], al[4], bh[4], bl[4];
        #pragma unroll
        for (int mi = 0; mi < 4; ++mi) {
            int r = wm * 64 + mi * 16 + r15;
            if constexpr (AMODE == 2) {
                int s0 = (2 * q) ^ (r & 7), s1 = s0 ^ 1;
                const unsigned* base = (const unsigned*)smA + r * 32;
                uint4 a = *(const uint4*)(base + s0 * 4);
                uint4 b = *(const uint4*)(base + s1 * 4);
                unpack8(a, b, ah[mi], al[mi]);
            } else {
                ah[mi] = *(const short8*)((const unsigned short*)smA + (q * 128 + r) * 8);
                al[mi] = *(const short8*)((const unsigned short*)(smA + 8192) + (q * 128 + r) * 8);
            }
        }
        #pragma unroll
        for (int ni = 0; ni < 4; ++ni) {
            int r = wn * 64 + ni * 16 + r15;
            if constexpr (BMODE == 2) {
                int s0 = (2 * q) ^ (r & 7), s1 = s0 ^ 1;
                const unsigned* base = (const unsigned*)smB + r * 32;
                uint4 a = *(const uint4*)(base + s0 * 4);
                uint4 b = *(const uint4*)(base + s1 * 4);
                unpack8(a, b, bh[ni], bl[ni]);
            } else {
                bh[ni] = *(const short8*)(BhT + (q * 128 + r) * 8);
                bl[ni] = *(const short8*)(BlT + (q * 128 + r) * 8);
            }
        }
        #pragma unroll
        for (int mi = 0; mi < 4; ++mi)
            #pragma unroll
            for (int ni = 0; ni < 4; ++ni) {
                acc[mi][ni] = __builtin_amdgcn_mfma_f32_16x16x32_bf16(ah[mi], bh[ni], acc[mi][ni], 0, 0, 0);
                acc[mi][ni] = __builtin_amdgcn_mfma_f32_16x16x32_bf16(ah[mi], bl[ni], acc[mi][ni], 0, 0, 0);
                acc[mi][ni] = __builtin_amdgcn_mfma_f32_16x16x32_bf16(al[mi], bh[ni], acc[mi][ni], 0, 0, 0);
            }
        __syncthreads();
    }

    #pragma unroll
    for (int mi = 0; mi < 4; ++mi) {
        int gr0 = m0 + wm * 64 + mi * 16 + q * 4;
        #pragma unroll
        for (int ni = 0; ni < 4; ++ni) {
            int gc = n0 + wn * 64 + ni * 16 + r15;
            #pragma unroll
            for (int j = 0; j < 4; ++j) {
                int gr = gr0 + j;
                float b = BIAS_ROW ? bias[gr] : bias[gc];
                float v = gelu_exact(acc[mi][ni][j] + b);
                if constexpr (OUTF) outF[(size_t)gr * N + gc] = v;
                else                outP[(size_t)gr * N + gc] = packsplit(v);
            }
        }
    }
}

// ---------------------------------------------------------------------------
// MFMA attention (unchanged, proven): one wave per (window, head).
// ---------------------------------------------------------------------------
__global__ __launch_bounds__(256, 2)
void attn_mfma(const unsigned* __restrict__ Tp, const float* __restrict__ bias_table,
               unsigned* __restrict__ Yp) {
    __shared__ unsigned short Vh[4][32][72];
    __shared__ unsigned short Vl[4][32][72];
    __shared__ unsigned PHs[4][16][36];
    __shared__ unsigned PLs[4][16][36];

    const int tid = threadIdx.x, wid = tid >> 6, lane = tid & 63;
    const int pidx = blockIdx.x * 4 + wid;
    const int b2 = pidx / NHEADS, h = pidx - b2 * NHEADS;
    const size_t qoff = (size_t)b2 * 18816 + (size_t)h * 1568;
    const int r15 = lane & 15, g = lane >> 4;

    #pragma unroll
    for (int it = 0; it < 8; ++it) {
        int idx = it * 64 + lane;
        int t = idx >> 3, dq = idx & 7;
        int tc = t > 48 ? 48 : t;
        uint4 w = *(const uint4*)&Tp[2 * QL + qoff + (size_t)tc * HD + dq * 4];
        #pragma unroll
        for (int c = 0; c < 4; ++c) {
            unsigned pw = (c == 0) ? w.x : (c == 1) ? w.y : (c == 2) ? w.z : w.w;
            Vh[wid][dq * 4 + c][t] = (unsigned short)(pw >> 16);
            Vl[wid][dq * 4 + c][t] = (unsigned short)(pw & 0xffffu);
        }
    }
    __syncthreads();

    f32x4 S[4][4];
    int cS[4];
    #pragma unroll
    for (int st = 0; st < 4; ++st) {
        int s = st * 16 + r15; if (s > 48) s = 48;
        int sd = (s * 37) >> 8;
        cS[st] = 156 * (12 - (s - 6 * sd)) + h;
    }
    #pragma unroll
    for (int tt = 0; tt < 4; ++tt)
        #pragma unroll
        for (int r = 0; r < 4; ++r) {
            int t = tt * 16 + 4 * g + r; int tc2 = t > 48 ? 48 : t;
            int td = (tc2 * 37) >> 8;
            int at = 156 * (tc2 - 6 * td);
            #pragma unroll
            for (int st = 0; st < 4; ++st)
                S[tt][st][r] = bias_table[at + cS[st]];
        }

    short8 qh[4], qlo[4];
    #pragma unroll
    for (int st = 0; st < 4; ++st) {
        int s = st * 16 + r15; if (s > 48) s = 48;
        const unsigned* p = Tp + qoff + (size_t)s * HD + g * 8;
        uint4 a = *(const uint4*)p;
        uint4 b = *(const uint4*)(p + 4);
        unpack8(a, b, qh[st], qlo[st]);
    }
    #pragma unroll
    for (int tt = 0; tt < 4; ++tt) {
        int t = tt * 16 + r15; if (t > 48) t = 48;
        const unsigned* p = Tp + QL + qoff + (size_t)t * HD + g * 8;
        uint4 a = *(const uint4*)p;
        uint4 b = *(const uint4*)(p + 4);
        short8 kh, kl; unpack8(a, b, kh, kl);
        #pragma unroll
        for (int st = 0; st < 4; ++st) {
            S[tt][st] = __builtin_amdgcn_mfma_f32_16x16x32_bf16(kh, qh[st],  S[tt][st], 0, 0, 0);
            S[tt][st] = __builtin_amdgcn_mfma_f32_16x16x32_bf16(kh, qlo[st], S[tt][st], 0, 0, 0);
            S[tt][st] = __builtin_amdgcn_mfma_f32_16x16x32_bf16(kl, qh[st],  S[tt][st], 0, 0, 0);
        }
    }
    #pragma unroll
    for (int st = 0; st < 4; ++st) {
        S[3][st][0] = (g == 0) ? S[3][st][0] : -1e30f;
        S[3][st][1] = -1e30f; S[3][st][2] = -1e30f; S[3][st][3] = -1e30f;
    }
    float inv[4];
    #pragma unroll
    for (int st = 0; st < 4; ++st) {
        float mx = -1e30f;
        #pragma unroll
        for (int tt = 0; tt < 4; ++tt)
            #pragma unroll
            for (int r = 0; r < 4; ++r) mx = fmaxf(mx, S[tt][st][r]);
        mx = fmaxf(mx, __shfl_xor(mx, 16));
        mx = fmaxf(mx, __shfl_xor(mx, 32));
        float sm = 0.f;
        #pragma unroll
        for (int tt = 0; tt < 4; ++tt)
            #pragma unroll
            for (int r = 0; r < 4; ++r) {
                float e = __expf(S[tt][st][r] - mx);
                S[tt][st][r] = e; sm += e;
            }
        sm += __shfl_xor(sm, 16);
        sm += __shfl_xor(sm, 32);
        inv[st] = 1.0f / sm;
    }
    short8 vfh[2][2], vfl[2][2];
    #pragma unroll
    for (int dt = 0; dt < 2; ++dt)
        #pragma unroll
        for (int kc = 0; kc < 2; ++kc) {
            int d = dt * 16 + r15;
            vfh[dt][kc] = *(const short8*)&Vh[wid][d][kc * 32 + g * 8];
            vfl[dt][kc] = *(const short8*)&Vl[wid][d][kc * 32 + g * 8];
        }
    for (int st = 0; st < 4; ++st) {
        #pragma unroll
        for (int tt = 0; tt < 4; ++tt)
            #pragma unroll
            for (int rp = 0; rp < 2; ++rp) {
                float p0 = S[tt][st][2 * rp]     * inv[st];
                float p1 = S[tt][st][2 * rp + 1] * inv[st];
                unsigned h0 = bf16rn_bits(p0), h1 = bf16rn_bits(p1);
                unsigned l0 = bf16rn_bits(p0 - __uint_as_float(h0));
                unsigned l1 = bf16rn_bits(p1 - __uint_as_float(h1));
                int w = tt * 8 + 2 * g + rp;
                int wsw = (((w >> 2) ^ (r15 & 7)) << 2) + (w & 3);
                PHs[wid][r15][wsw] = __builtin_amdgcn_perm(h1, h0, 0x07060302u);
                PLs[wid][r15][wsw] = __builtin_amdgcn_perm(l1, l0, 0x07060302u);
            }
        __syncthreads();
        f32x4 o[2] = {};
        #pragma unroll
        for (int kc = 0; kc < 2; ++kc) {
            int grp = (4 * kc + g) ^ (r15 & 7);
            short8 ph = *(const short8*)&PHs[wid][r15][grp * 4];
            short8 pl = *(const short8*)&PLs[wid][r15][grp * 4];
            #pragma unroll
            for (int dt = 0; dt < 2; ++dt) {
                o[dt] = __builtin_amdgcn_mfma_f32_16x16x32_bf16(ph, vfh[dt][kc], o[dt], 0, 0, 0);
                o[dt] = __builtin_amdgcn_mfma_f32_16x16x32_bf16(ph, vfl[dt][kc], o[dt], 0, 0, 0);
                o[dt] = __builtin_amdgcn_mfma_f32_16x16x32_bf16(pl, vfh[dt][kc], o[dt], 0, 0, 0);
            }
        }
        #pragma unroll
        for (int r = 0; r < 4; ++r) {
            int s = st * 16 + 4 * g + r;
            if (s < SEQ) {
                size_t ob = ((size_t)b2 * SEQ + s) * CDIM + h * HD + r15;
                Yp[ob]      = packsplit(o[0][r]);
                Yp[ob + 16] = packsplit(o[1][r]);
            }
        }
        __syncthreads();
    }
}

extern "C" void kernel_launch(void* const* d_in, const int* in_sizes, int n_in,
                              void* d_out, int out_size, void* d_ws, size_t ws_size,
                              hipStream_t stream) {
    const float* x          = (const float*)d_in[0];
    const float* w_qkv      = (const float*)d_in[1];
    const float* b_qkv      = (const float*)d_in[2];
    const float* bias_table = (const float*)d_in[3];
    const float* w_out      = (const float*)d_in[4];
    const float* b_out      = (const float*)d_in[5];
    unsigned* Tp = (unsigned*)d_ws;
    const size_t TPW = 3 * QL;

    const size_t WQG = 48ULL * MPAD * 8;     // u16 per wq granule array (padded)
    const size_t WOG = 48ULL * CDIM * 8;     // u16 per wo granule array
    const size_t need = TPW * 4ULL + 2 * WQG * 2ULL + 2 * WOG * 2ULL;

    if (ws_size >= need) {
        unsigned short* wq_hi = (unsigned short*)((char*)d_ws + TPW * 4ULL);
        unsigned short* wq_lo = wq_hi + WQG;
        unsigned short* wo_hi = wq_lo + WQG;
        unsigned short* wo_lo = wo_hi + WOG;
        unsigned* xp = (unsigned*)d_out;

        prep_w<<<(MPAD * 48 + 255) / 256, 256, 0, stream>>>(w_qkv, wq_hi, wq_lo, NH3, MPAD, CDIM);
        prep_w<<<(CDIM * 48 + 255) / 256, 256, 0, stream>>>(w_out, wo_hi, wo_lo, CDIM, CDIM, CDIM);
        prep_x<<<(NTOK * CDIM / 8 + 255) / 256, 256, 0, stream>>>(x, xp, NTOK * CDIM / 8);

        // 1) T = gelu(wq^T @ x^T + b_qkv): 8-phase 256^2 pipeline, grid 5*784
        gemm8p<<<3920, 512, 0, stream>>>(wq_hi, wq_lo, xp, b_qkv, Tp, NTOK, CDIM, NH3);

        // 2) attention -> Y0 packed in d_out
        attn_mfma<<<12288, 256, 0, stream>>>(Tp, bias_table, (unsigned*)d_out);

        // 3) Y1 = gelu(Y0 @ wout + b_out) -> Tp (packed)
        gemm_b3<2, 1, false, false><<<dim3(3, 1568), 256, 0, stream>>>(
            nullptr, nullptr, nullptr, (unsigned*)d_out, nullptr, wo_hi, wo_lo, nullptr,
            b_out, nullptr, Tp, NTOK, CDIM, CDIM, 0, 0);

        // 4) out = gelu(Y1 @ wout + b_out)
        gemm_b3<2, 1, false, true><<<dim3(3, 1568), 256, 0, stream>>>(
            nullptr, nullptr, nullptr, Tp, nullptr, wo_hi, wo_lo, nullptr,
            b_out, (float*)d_out, nullptr, NTOK, CDIM, CDIM, 0, 0);
    } else {
        // fallback (R4-proven): weights in d_out / dead T third; x staged fp32 inline
        unsigned short* wq_hi = (unsigned short*)d_out;
        unsigned short* wq_lo = wq_hi + (size_t)NH3 * CDIM;
        unsigned short* wo_hi = (unsigned short*)(Tp + QL);
        unsigned short* wo_lo = wo_hi + (size_t)CDIM * CDIM;

        prep_w<<<(NH3 * 48 + 255) / 256, 256, 0, stream>>>(w_qkv, wq_hi, wq_lo, NH3, NH3, CDIM);

        gemm_b3<1, 0, true, false><<<14112, 256, 0, stream>>>(
            nullptr, wq_hi, wq_lo, nullptr, x, nullptr, nullptr, nullptr,
            b_qkv, nullptr, Tp, NH3, NTOK, CDIM, 9, 1764);

        attn_mfma<<<12288, 256, 0, stream>>>(Tp, bias_table, (unsigned*)d_out);

        prep_w<<<(CDIM * 48 + 255) / 256, 256, 0, stream>>>(w_out, wo_hi, wo_lo, CDIM, CDIM, CDIM);

        gemm_b3<2, 1, false, false><<<dim3(3, 1568), 256, 0, stream>>>(
            nullptr, nullptr, nullptr, (unsigned*)d_out, nullptr, wo_hi, wo_lo, nullptr,
            b_out, nullptr, Tp, NTOK, CDIM, CDIM, 0, 0);

        gemm_b3<2, 1, false, true><<<dim3(3, 1568), 256, 0, stream>>>(
            nullptr, nullptr, nullptr, Tp, nullptr, wo_hi, wo_lo, nullptr,
            b_out, (float*)d_out, nullptr, NTOK, CDIM, CDIM, 0, 0);
    }
}

// Round 8
// 1613.229 us; speedup vs baseline: 1.1942x; 1.1942x over previous
//
#include <hip/hip_runtime.h>
#include <math.h>

#define NTOK 200704          // B*S = 4096*49
#define CDIM 384
#define NH3  1152            // 3*C
#define NHEADS 12
#define HD   32
#define SEQ  49
#define QL   77070336ULL     // CDIM*NTOK (one third of T)

typedef __attribute__((ext_vector_type(8))) short short8;
typedef __attribute__((ext_vector_type(4))) float f32x4;
typedef __attribute__((ext_vector_type(16))) float f32x16;

__device__ __forceinline__ float gelu_exact(float x) {
    return 0.5f * x * (1.0f + erff(x * 0.70710678118654752f));
}
__device__ __forceinline__ unsigned bf16rn_bits(float x) {
    unsigned u = __float_as_uint(x);
    return (u + 0x7fffu + ((u >> 16) & 1u)) & 0xffff0000u;
}
__device__ __forceinline__ unsigned packsplit(float x) {
    unsigned hb = bf16rn_bits(x);
    float r = x - __uint_as_float(hb);
    unsigned lb = bf16rn_bits(r);
    return hb | (lb >> 16);
}
__device__ __forceinline__ void gl_lds16(const void* g, void* l) {
    __builtin_amdgcn_global_load_lds((const __attribute__((address_space(1))) void*)g,
                                     (__attribute__((address_space(3))) void*)l, 16, 0, 0);
}
union F8 { short8 v; unsigned u[4]; };
__device__ __forceinline__ void unpack8(uint4 a, uint4 b, short8 &h, short8 &l) {
    F8 H, L;
    H.u[0] = __builtin_amdgcn_perm(a.y, a.x, 0x07060302u);
    H.u[1] = __builtin_amdgcn_perm(a.w, a.z, 0x07060302u);
    H.u[2] = __builtin_amdgcn_perm(b.y, b.x, 0x07060302u);
    H.u[3] = __builtin_amdgcn_perm(b.w, b.z, 0x07060302u);
    L.u[0] = __builtin_amdgcn_perm(a.y, a.x, 0x05040100u);
    L.u[1] = __builtin_amdgcn_perm(a.w, a.z, 0x05040100u);
    L.u[2] = __builtin_amdgcn_perm(b.y, b.x, 0x05040100u);
    L.u[3] = __builtin_amdgcn_perm(b.w, b.z, 0x05040100u);
    h = H.v; l = L.v;
}

// ---------------------------------------------------------------------------
// prep_w: w (Kdim x Mdim row-major fp32) -> hi/lo bf16 granules [koct][Mdim][8]
// ---------------------------------------------------------------------------
__global__ __launch_bounds__(256)
void prep_w(const float* __restrict__ w, unsigned short* __restrict__ hi,
            unsigned short* __restrict__ lo, int Mdim, int Kdim) {
    int idx = blockIdx.x * 256 + threadIdx.x;
    int total = Mdim * (Kdim >> 3);
    if (idx >= total) return;
    int koct = idx / Mdim, m = idx - koct * Mdim;
    unsigned short h8[8], l8[8];
    #pragma unroll
    for (int j = 0; j < 8; ++j) {
        float v = w[(size_t)(koct * 8 + j) * Mdim + m];
        unsigned hb = bf16rn_bits(v);
        h8[j] = (unsigned short)(hb >> 16);
        l8[j] = (unsigned short)(bf16rn_bits(v - __uint_as_float(hb)) >> 16);
    }
    size_t o = (size_t)idx * 8;
    *(short8*)&hi[o] = *(short8*)h8;
    *(short8*)&lo[o] = *(short8*)l8;
}

// prep_x: fp32 row-major -> packed-split u32, same layout
__global__ __launch_bounds__(256)
void prep_x(const float* __restrict__ x, unsigned* __restrict__ xp, int total8) {
    int idx = blockIdx.x * 256 + threadIdx.x;
    if (idx >= total8) return;
    size_t e = (size_t)idx * 8;
    float4 v0 = *(const float4*)&x[e];
    float4 v1 = *(const float4*)&x[e + 4];
    *(uint4*)&xp[e]     = make_uint4(packsplit(v0.x), packsplit(v0.y), packsplit(v0.z), packsplit(v0.w));
    *(uint4*)&xp[e + 4] = make_uint4(packsplit(v1.x), packsplit(v1.y), packsplit(v1.z), packsplit(v1.w));
}

// ---------------------------------------------------------------------------
// bf16x3 GEMM, 128x128 tile, BK=32, 4 waves (2x2 of 64x64), single-buffered
// LDS (R4-proven structure), MFMA shape 32x32x16 (2 frags/dim per wave).
// MODE 0: fp32 source (rows x K), inline split  (B side only, fallback)
// MODE 1: pre-split granule arrays [koct][LD][8] hi/lo u16, via global_load_lds
// MODE 2: packed u32 (hi|lo) row-major [rows][K], via global_load_lds + v_perm
// ---------------------------------------------------------------------------
template<int AMODE, int BMODE, bool BIAS_ROW, bool OUTF>
__global__ __launch_bounds__(256, 2)
void gemm_b3(const float* __restrict__ Af,
             const unsigned short* __restrict__ Agh, const unsigned short* __restrict__ Agl,
             const unsigned* __restrict__ Ap,
             const float* __restrict__ Bf,
             const unsigned short* __restrict__ Bgh, const unsigned short* __restrict__ Bgl,
             const unsigned* __restrict__ Bp,
             const float* __restrict__ bias, float* __restrict__ outF,
             unsigned* __restrict__ outP,
             int M, int N, int K, int nMt, int cpx) {
    __shared__ char smA[16384];
    __shared__ char smB[16384];
    const int tid = threadIdx.x;
    int m0, n0;
    if (cpx > 0) {  // XCD-chunked 1D grid: consecutive wg share the token tile
        int wg = (blockIdx.x & 7) * cpx + (blockIdx.x >> 3);
        m0 = (wg % nMt) * 128;
        n0 = (wg / nMt) * 128;
    } else {
        n0 = blockIdx.x * 128;
        m0 = blockIdx.y * 128;
    }
    const int wid = tid >> 6, lane = tid & 63;
    const int wm = wid >> 1, wn = wid & 1;
    const int l31 = lane & 31, lh = lane >> 5;
    const int f_r = tid >> 3, f_f4 = tid & 7;
    const int f_qq = f_f4 >> 1, f_half = (f_f4 & 1) * 8;

    unsigned short* BhT = (unsigned short*)smB;
    unsigned short* BlT = (unsigned short*)(smB + 8192);

    f32x16 acc[2][2] = {};

    for (int k0 = 0; k0 < K; k0 += 32) {
        const int kb = k0 >> 3;
        // ---------------- stage (unchanged from R4) ----------------
        if constexpr (AMODE == 1) {
            #pragma unroll
            for (int it = 0; it < 2; ++it) {
                int g = it * 256 + tid;
                int qq = g >> 7, r = g & 127;
                size_t src = ((size_t)(kb + qq) * M + m0 + r) * 8;
                gl_lds16(Agh + src, smA + g * 16);
                gl_lds16(Agl + src, smA + 8192 + g * 16);
            }
        } else if constexpr (AMODE == 2) {
            #pragma unroll
            for (int it = 0; it < 4; ++it) {
                int row = it * 32 + (tid >> 3);
                int slot = (tid & 7) ^ (row & 7);
                gl_lds16(Ap + (size_t)(m0 + row) * K + k0 + slot * 4,
                         smA + (size_t)(it * 256 + tid) * 16);
            }
        }
        if constexpr (BMODE == 1) {
            #pragma unroll
            for (int it = 0; it < 2; ++it) {
                int g = it * 256 + tid;
                int qq = g >> 7, r = g & 127;
                size_t src = ((size_t)(kb + qq) * N + n0 + r) * 8;
                gl_lds16(Bgh + src, smB + g * 16);
                gl_lds16(Bgl + src, smB + 8192 + g * 16);
            }
        } else if constexpr (BMODE == 2) {
            #pragma unroll
            for (int it = 0; it < 4; ++it) {
                int row = it * 32 + (tid >> 3);
                int slot = (tid & 7) ^ (row & 7);
                gl_lds16(Bp + (size_t)(n0 + row) * K + k0 + slot * 4,
                         smB + (size_t)(it * 256 + tid) * 16);
            }
        } else {
            #pragma unroll
            for (int it = 0; it < 4; ++it) {
                int r = it * 32 + f_r;
                float4 v = *(const float4*)&Bf[(size_t)(n0 + r) * K + k0 + f_f4 * 4];
                unsigned hb0 = bf16rn_bits(v.x), hb1 = bf16rn_bits(v.y);
                unsigned hb2 = bf16rn_bits(v.z), hb3 = bf16rn_bits(v.w);
                unsigned l0 = bf16rn_bits(v.x - __uint_as_float(hb0)) >> 16;
                unsigned l1 = bf16rn_bits(v.y - __uint_as_float(hb1)) >> 16;
                unsigned l2 = bf16rn_bits(v.z - __uint_as_float(hb2)) >> 16;
                unsigned l3 = bf16rn_bits(v.w - __uint_as_float(hb3)) >> 16;
                unsigned h0 = hb0 >> 16, h1 = hb1 >> 16, h2 = hb2 >> 16, h3 = hb3 >> 16;
                *(uint2*)((char*)(BhT + (f_qq * 128 + r) * 8) + f_half) =
                    make_uint2(h0 | (h1 << 16), h2 | (h3 << 16));
                *(uint2*)((char*)(BlT + (f_qq * 128 + r) * 8) + f_half) =
                    make_uint2(l0 | (l1 << 16), l2 | (l3 << 16));
            }
        }
        __syncthreads();

        // -------- fragment loads: 32x32x16 lane layout row=l31, k=lh*8+j ----
        // k-octet for sub-step ko (K=16 each): o = 2*ko + lh
        short8 ah[2][2], al[2][2], bh[2][2], bl[2][2];
        #pragma unroll
        for (int mi = 0; mi < 2; ++mi) {
            int r = wm * 64 + mi * 32 + l31;
            #pragma unroll
            for (int ko = 0; ko < 2; ++ko) {
                int o = 2 * ko + lh;
                if constexpr (AMODE == 2) {
                    int s0 = (2 * o) ^ (r & 7), s1 = s0 ^ 1;
                    const unsigned* base = (const unsigned*)smA + r * 32;
                    uint4 a = *(const uint4*)(base + s0 * 4);
                    uint4 b = *(const uint4*)(base + s1 * 4);
                    unpack8(a, b, ah[mi][ko], al[mi][ko]);
                } else {
                    ah[mi][ko] = *(const short8*)((const unsigned short*)smA + (o * 128 + r) * 8);
                    al[mi][ko] = *(const short8*)((const unsigned short*)(smA + 8192) + (o * 128 + r) * 8);
                }
            }
        }
        #pragma unroll
        for (int ni = 0; ni < 2; ++ni) {
            int r = wn * 64 + ni * 32 + l31;
            #pragma unroll
            for (int ko = 0; ko < 2; ++ko) {
                int o = 2 * ko + lh;
                if constexpr (BMODE == 2) {
                    int s0 = (2 * o) ^ (r & 7), s1 = s0 ^ 1;
                    const unsigned* base = (const unsigned*)smB + r * 32;
                    uint4 a = *(const uint4*)(base + s0 * 4);
                    uint4 b = *(const uint4*)(base + s1 * 4);
                    unpack8(a, b, bh[ni][ko], bl[ni][ko]);
                } else {
                    bh[ni][ko] = *(const short8*)(BhT + (o * 128 + r) * 8);
                    bl[ni][ko] = *(const short8*)(BlT + (o * 128 + r) * 8);
                }
            }
        }
        // -------- MFMA (bf16x3, 32x32x16) --------
        #pragma unroll
        for (int ko = 0; ko < 2; ++ko)
            #pragma unroll
            for (int mi = 0; mi < 2; ++mi)
                #pragma unroll
                for (int ni = 0; ni < 2; ++ni) {
                    acc[mi][ni] = __builtin_amdgcn_mfma_f32_32x32x16_bf16(ah[mi][ko], bh[ni][ko], acc[mi][ni], 0, 0, 0);
                    acc[mi][ni] = __builtin_amdgcn_mfma_f32_32x32x16_bf16(ah[mi][ko], bl[ni][ko], acc[mi][ni], 0, 0, 0);
                    acc[mi][ni] = __builtin_amdgcn_mfma_f32_32x32x16_bf16(al[mi][ko], bh[ni][ko], acc[mi][ni], 0, 0, 0);
                }
        __syncthreads();
    }

    // ---- epilogue: C/D layout col=l31, row=(reg&3)+8*(reg>>2)+4*lh ----
    #pragma unroll
    for (int mi = 0; mi < 2; ++mi) {
        #pragma unroll
        for (int ni = 0; ni < 2; ++ni) {
            int gc = n0 + wn * 64 + ni * 32 + l31;
            #pragma unroll
            for (int reg = 0; reg < 16; ++reg) {
                int gr = m0 + wm * 64 + mi * 32 + (reg & 3) + 8 * (reg >> 2) + 4 * lh;
                float b = BIAS_ROW ? bias[gr] : bias[gc];
                float v = gelu_exact(acc[mi][ni][reg] + b);
                if constexpr (OUTF) outF[(size_t)gr * N + gc] = v;
                else                outP[(size_t)gr * N + gc] = packsplit(v);
            }
        }
    }
}

// ---------------------------------------------------------------------------
// MFMA attention (unchanged, proven): one wave per (window, head).
// ---------------------------------------------------------------------------
__global__ __launch_bounds__(256, 2)
void attn_mfma(const unsigned* __restrict__ Tp, const float* __restrict__ bias_table,
               unsigned* __restrict__ Yp) {
    __shared__ unsigned short Vh[4][32][72];
    __shared__ unsigned short Vl[4][32][72];
    __shared__ unsigned PHs[4][16][36];
    __shared__ unsigned PLs[4][16][36];

    const int tid = threadIdx.x, wid = tid >> 6, lane = tid & 63;
    const int pidx = blockIdx.x * 4 + wid;
    const int b2 = pidx / NHEADS, h = pidx - b2 * NHEADS;
    const size_t qoff = (size_t)b2 * 18816 + (size_t)h * 1568;
    const int r15 = lane & 15, g = lane >> 4;

    #pragma unroll
    for (int it = 0; it < 8; ++it) {
        int idx = it * 64 + lane;
        int t = idx >> 3, dq = idx & 7;
        int tc = t > 48 ? 48 : t;
        uint4 w = *(const uint4*)&Tp[2 * QL + qoff + (size_t)tc * HD + dq * 4];
        #pragma unroll
        for (int c = 0; c < 4; ++c) {
            unsigned pw = (c == 0) ? w.x : (c == 1) ? w.y : (c == 2) ? w.z : w.w;
            Vh[wid][dq * 4 + c][t] = (unsigned short)(pw >> 16);
            Vl[wid][dq * 4 + c][t] = (unsigned short)(pw & 0xffffu);
        }
    }
    __syncthreads();

    f32x4 S[4][4];
    int cS[4];
    #pragma unroll
    for (int st = 0; st < 4; ++st) {
        int s = st * 16 + r15; if (s > 48) s = 48;
        int sd = (s * 37) >> 8;
        cS[st] = 156 * (12 - (s - 6 * sd)) + h;
    }
    #pragma unroll
    for (int tt = 0; tt < 4; ++tt)
        #pragma unroll
        for (int r = 0; r < 4; ++r) {
            int t = tt * 16 + 4 * g + r; int tc2 = t > 48 ? 48 : t;
            int td = (tc2 * 37) >> 8;
            int at = 156 * (tc2 - 6 * td);
            #pragma unroll
            for (int st = 0; st < 4; ++st)
                S[tt][st][r] = bias_table[at + cS[st]];
        }

    short8 qh[4], qlo[4];
    #pragma unroll
    for (int st = 0; st < 4; ++st) {
        int s = st * 16 + r15; if (s > 48) s = 48;
        const unsigned* p = Tp + qoff + (size_t)s * HD + g * 8;
        uint4 a = *(const uint4*)p;
        uint4 b = *(const uint4*)(p + 4);
        unpack8(a, b, qh[st], qlo[st]);
    }
    #pragma unroll
    for (int tt = 0; tt < 4; ++tt) {
        int t = tt * 16 + r15; if (t > 48) t = 48;
        const unsigned* p = Tp + QL + qoff + (size_t)t * HD + g * 8;
        uint4 a = *(const uint4*)p;
        uint4 b = *(const uint4*)(p + 4);
        short8 kh, kl; unpack8(a, b, kh, kl);
        #pragma unroll
        for (int st = 0; st < 4; ++st) {
            S[tt][st] = __builtin_amdgcn_mfma_f32_16x16x32_bf16(kh, qh[st],  S[tt][st], 0, 0, 0);
            S[tt][st] = __builtin_amdgcn_mfma_f32_16x16x32_bf16(kh, qlo[st], S[tt][st], 0, 0, 0);
            S[tt][st] = __builtin_amdgcn_mfma_f32_16x16x32_bf16(kl, qh[st],  S[tt][st], 0, 0, 0);
        }
    }
    #pragma unroll
    for (int st = 0; st < 4; ++st) {
        S[3][st][0] = (g == 0) ? S[3][st][0] : -1e30f;
        S[3][st][1] = -1e30f; S[3][st][2] = -1e30f; S[3][st][3] = -1e30f;
    }
    float inv[4];
    #pragma unroll
    for (int st = 0; st < 4; ++st) {
        float mx = -1e30f;
        #pragma unroll
        for (int tt = 0; tt < 4; ++tt)
            #pragma unroll
            for (int r = 0; r < 4; ++r) mx = fmaxf(mx, S[tt][st][r]);
        mx = fmaxf(mx, __shfl_xor(mx, 16));
        mx = fmaxf(mx, __shfl_xor(mx, 32));
        float sm = 0.f;
        #pragma unroll
        for (int tt = 0; tt < 4; ++tt)
            #pragma unroll
            for (int r = 0; r < 4; ++r) {
                float e = __expf(S[tt][st][r] - mx);
                S[tt][st][r] = e; sm += e;
            }
        sm += __shfl_xor(sm, 16);
        sm += __shfl_xor(sm, 32);
        inv[st] = 1.0f / sm;
    }
    short8 vfh[2][2], vfl[2][2];
    #pragma unroll
    for (int dt = 0; dt < 2; ++dt)
        #pragma unroll
        for (int kc = 0; kc < 2; ++kc) {
            int d = dt * 16 + r15;
            vfh[dt][kc] = *(const short8*)&Vh[wid][d][kc * 32 + g * 8];
            vfl[dt][kc] = *(const short8*)&Vl[wid][d][kc * 32 + g * 8];
        }
    for (int st = 0; st < 4; ++st) {
        #pragma unroll
        for (int tt = 0; tt < 4; ++tt)
            #pragma unroll
            for (int rp = 0; rp < 2; ++rp) {
                float p0 = S[tt][st][2 * rp]     * inv[st];
                float p1 = S[tt][st][2 * rp + 1] * inv[st];
                unsigned h0 = bf16rn_bits(p0), h1 = bf16rn_bits(p1);
                unsigned l0 = bf16rn_bits(p0 - __uint_as_float(h0));
                unsigned l1 = bf16rn_bits(p1 - __uint_as_float(h1));
                int w = tt * 8 + 2 * g + rp;
                int wsw = (((w >> 2) ^ (r15 & 7)) << 2) + (w & 3);
                PHs[wid][r15][wsw] = __builtin_amdgcn_perm(h1, h0, 0x07060302u);
                PLs[wid][r15][wsw] = __builtin_amdgcn_perm(l1, l0, 0x07060302u);
            }
        __syncthreads();
        f32x4 o[2] = {};
        #pragma unroll
        for (int kc = 0; kc < 2; ++kc) {
            int grp = (4 * kc + g) ^ (r15 & 7);
            short8 ph = *(const short8*)&PHs[wid][r15][grp * 4];
            short8 pl = *(const short8*)&PLs[wid][r15][grp * 4];
            #pragma unroll
            for (int dt = 0; dt < 2; ++dt) {
                o[dt] = __builtin_amdgcn_mfma_f32_16x16x32_bf16(ph, vfh[dt][kc], o[dt], 0, 0, 0);
                o[dt] = __builtin_amdgcn_mfma_f32_16x16x32_bf16(ph, vfl[dt][kc], o[dt], 0, 0, 0);
                o[dt] = __builtin_amdgcn_mfma_f32_16x16x32_bf16(pl, vfh[dt][kc], o[dt], 0, 0, 0);
            }
        }
        #pragma unroll
        for (int r = 0; r < 4; ++r) {
            int s = st * 16 + 4 * g + r;
            if (s < SEQ) {
                size_t ob = ((size_t)b2 * SEQ + s) * CDIM + h * HD + r15;
                Yp[ob]      = packsplit(o[0][r]);
                Yp[ob + 16] = packsplit(o[1][r]);
            }
        }
        __syncthreads();
    }
}

extern "C" void kernel_launch(void* const* d_in, const int* in_sizes, int n_in,
                              void* d_out, int out_size, void* d_ws, size_t ws_size,
                              hipStream_t stream) {
    const float* x          = (const float*)d_in[0];
    const float* w_qkv      = (const float*)d_in[1];
    const float* b_qkv      = (const float*)d_in[2];
    const float* bias_table = (const float*)d_in[3];
    const float* w_out      = (const float*)d_in[4];
    const float* b_out      = (const float*)d_in[5];
    unsigned* Tp = (unsigned*)d_ws;
    const size_t TPW = 3 * QL;

    const size_t need = TPW * 4ULL + (size_t)NH3 * CDIM * 4ULL + (size_t)CDIM * CDIM * 4ULL;

    if (ws_size >= need) {
        unsigned short* wq_hi = (unsigned short*)((char*)d_ws + TPW * 4ULL);
        unsigned short* wq_lo = wq_hi + (size_t)NH3 * CDIM;
        unsigned short* wo_hi = wq_lo + (size_t)NH3 * CDIM;
        unsigned short* wo_lo = wo_hi + (size_t)CDIM * CDIM;
        unsigned* xp = (unsigned*)d_out;

        prep_w<<<(NH3 * 48 + 255) / 256, 256, 0, stream>>>(w_qkv, wq_hi, wq_lo, NH3, CDIM);
        prep_w<<<(CDIM * 48 + 255) / 256, 256, 0, stream>>>(w_out, wo_hi, wo_lo, CDIM, CDIM);
        prep_x<<<(NTOK * CDIM / 8 + 255) / 256, 256, 0, stream>>>(x, xp, NTOK * CDIM / 8);

        gemm_b3<1, 2, true, false><<<14112, 256, 0, stream>>>(
            nullptr, wq_hi, wq_lo, nullptr, nullptr, nullptr, nullptr, xp,
            b_qkv, nullptr, Tp, NH3, NTOK, CDIM, 9, 1764);

        attn_mfma<<<12288, 256, 0, stream>>>(Tp, bias_table, (unsigned*)d_out);

        gemm_b3<2, 1, false, false><<<dim3(3, 1568), 256, 0, stream>>>(
            nullptr, nullptr, nullptr, (unsigned*)d_out, nullptr, wo_hi, wo_lo, nullptr,
            b_out, nullptr, Tp, NTOK, CDIM, CDIM, 0, 0);

        gemm_b3<2, 1, false, true><<<dim3(3, 1568), 256, 0, stream>>>(
            nullptr, nullptr, nullptr, Tp, nullptr, wo_hi, wo_lo, nullptr,
            b_out, (float*)d_out, nullptr, NTOK, CDIM, CDIM, 0, 0);
    } else {
        // fallback: weights in d_out / dead T third; x staged fp32 inline
        unsigned short* wq_hi = (unsigned short*)d_out;
        unsigned short* wq_lo = wq_hi + (size_t)NH3 * CDIM;
        unsigned short* wo_hi = (unsigned short*)(Tp + QL);
        unsigned short* wo_lo = wo_hi + (size_t)CDIM * CDIM;

        prep_w<<<(NH3 * 48 + 255) / 256, 256, 0, stream>>>(w_qkv, wq_hi, wq_lo, NH3, CDIM);

        gemm_b3<1, 0, true, false><<<14112, 256, 0, stream>>>(
            nullptr, wq_hi, wq_lo, nullptr, x, nullptr, nullptr, nullptr,
            b_qkv, nullptr, Tp, NH3, NTOK, CDIM, 9, 1764);

        attn_mfma<<<12288, 256, 0, stream>>>(Tp, bias_table, (unsigned*)d_out);

        prep_w<<<(CDIM * 48 + 255) / 256, 256, 0, stream>>>(w_out, wo_hi, wo_lo, CDIM, CDIM);

        gemm_b3<2, 1, false, false><<<dim3(3, 1568), 256, 0, stream>>>(
            nullptr, nullptr, nullptr, (unsigned*)d_out, nullptr, wo_hi, wo_lo, nullptr,
            b_out, nullptr, Tp, NTOK, CDIM, CDIM, 0, 0);

        gemm_b3<2, 1, false, true><<<dim3(3, 1568), 256, 0, stream>>>(
            nullptr, nullptr, nullptr, Tp, nullptr, wo_hi, wo_lo, nullptr,
            b_out, (float*)d_out, nullptr, NTOK, CDIM, CDIM, 0, 0);
    }
}

// Round 9
// 1553.927 us; speedup vs baseline: 1.2398x; 1.0382x over previous
//
#include <hip/hip_runtime.h>
#include <math.h>

#define NTOK 200704          // B*S = 4096*49
#define CDIM 384
#define NH3  1152            // 3*C
#define NHEADS 12
#define HD   32
#define SEQ  49
#define QL   77070336ULL     // CDIM*NTOK (one third of T)

typedef __attribute__((ext_vector_type(8))) short short8;
typedef __attribute__((ext_vector_type(4))) float f32x4;
typedef __attribute__((ext_vector_type(16))) float f32x16;

__device__ __forceinline__ float gelu_exact(float x) {
    return 0.5f * x * (1.0f + erff(x * 0.70710678118654752f));
}
__device__ __forceinline__ unsigned bf16rn_bits(float x) {
    unsigned u = __float_as_uint(x);
    return (u + 0x7fffu + ((u >> 16) & 1u)) & 0xffff0000u;
}
__device__ __forceinline__ unsigned packsplit(float x) {
    unsigned hb = bf16rn_bits(x);
    float r = x - __uint_as_float(hb);
    unsigned lb = bf16rn_bits(r);
    return hb | (lb >> 16);
}
__device__ __forceinline__ void gl_lds16(const void* g, void* l) {
    __builtin_amdgcn_global_load_lds((const __attribute__((address_space(1))) void*)g,
                                     (__attribute__((address_space(3))) void*)l, 16, 0, 0);
}
union F8 { short8 v; unsigned u[4]; };
__device__ __forceinline__ void unpack8(uint4 a, uint4 b, short8 &h, short8 &l) {
    F8 H, L;
    H.u[0] = __builtin_amdgcn_perm(a.y, a.x, 0x07060302u);
    H.u[1] = __builtin_amdgcn_perm(a.w, a.z, 0x07060302u);
    H.u[2] = __builtin_amdgcn_perm(b.y, b.x, 0x07060302u);
    H.u[3] = __builtin_amdgcn_perm(b.w, b.z, 0x07060302u);
    L.u[0] = __builtin_amdgcn_perm(a.y, a.x, 0x05040100u);
    L.u[1] = __builtin_amdgcn_perm(a.w, a.z, 0x05040100u);
    L.u[2] = __builtin_amdgcn_perm(b.y, b.x, 0x05040100u);
    L.u[3] = __builtin_amdgcn_perm(b.w, b.z, 0x05040100u);
    h = H.v; l = L.v;
}

// ---------------------------------------------------------------------------
// prep_w: w (Kdim x Mdim row-major fp32) -> hi/lo bf16 granules [koct][Mdim][8]
// ---------------------------------------------------------------------------
__global__ __launch_bounds__(256)
void prep_w(const float* __restrict__ w, unsigned short* __restrict__ hi,
            unsigned short* __restrict__ lo, int Mdim, int Kdim) {
    int idx = blockIdx.x * 256 + threadIdx.x;
    int total = Mdim * (Kdim >> 3);
    if (idx >= total) return;
    int koct = idx / Mdim, m = idx - koct * Mdim;
    unsigned short h8[8], l8[8];
    #pragma unroll
    for (int j = 0; j < 8; ++j) {
        float v = w[(size_t)(koct * 8 + j) * Mdim + m];
        unsigned hb = bf16rn_bits(v);
        h8[j] = (unsigned short)(hb >> 16);
        l8[j] = (unsigned short)(bf16rn_bits(v - __uint_as_float(hb)) >> 16);
    }
    size_t o = (size_t)idx * 8;
    *(short8*)&hi[o] = *(short8*)h8;
    *(short8*)&lo[o] = *(short8*)l8;
}

// prep_x: fp32 row-major -> packed-split u32, same layout
__global__ __launch_bounds__(256)
void prep_x(const float* __restrict__ x, unsigned* __restrict__ xp, int total8) {
    int idx = blockIdx.x * 256 + threadIdx.x;
    if (idx >= total8) return;
    size_t e = (size_t)idx * 8;
    float4 v0 = *(const float4*)&x[e];
    float4 v1 = *(const float4*)&x[e + 4];
    *(uint4*)&xp[e]     = make_uint4(packsplit(v0.x), packsplit(v0.y), packsplit(v0.z), packsplit(v0.w));
    *(uint4*)&xp[e + 4] = make_uint4(packsplit(v1.x), packsplit(v1.y), packsplit(v1.z), packsplit(v1.w));
}

// ---------------------------------------------------------------------------
// bf16x3 GEMM, 128x128 tile, BK=32, 4 waves (2x2 of 64x64), single-buffered
// LDS, MFMA 32x32x16. Launch-bounds min-waves raised to 4 (R9).
// ---------------------------------------------------------------------------
template<int AMODE, int BMODE, bool BIAS_ROW, bool OUTF>
__global__ __launch_bounds__(256, 4)
void gemm_b3(const float* __restrict__ Af,
             const unsigned short* __restrict__ Agh, const unsigned short* __restrict__ Agl,
             const unsigned* __restrict__ Ap,
             const float* __restrict__ Bf,
             const unsigned short* __restrict__ Bgh, const unsigned short* __restrict__ Bgl,
             const unsigned* __restrict__ Bp,
             const float* __restrict__ bias, float* __restrict__ outF,
             unsigned* __restrict__ outP,
             int M, int N, int K, int nMt, int cpx) {
    __shared__ char smA[16384];
    __shared__ char smB[16384];
    const int tid = threadIdx.x;
    int m0, n0;
    if (cpx > 0) {  // XCD-chunked 1D grid: consecutive wg share the token tile
        int wg = (blockIdx.x & 7) * cpx + (blockIdx.x >> 3);
        m0 = (wg % nMt) * 128;
        n0 = (wg / nMt) * 128;
    } else {
        n0 = blockIdx.x * 128;
        m0 = blockIdx.y * 128;
    }
    const int wid = tid >> 6, lane = tid & 63;
    const int wm = wid >> 1, wn = wid & 1;
    const int l31 = lane & 31, lh = lane >> 5;
    const int f_r = tid >> 3, f_f4 = tid & 7;
    const int f_qq = f_f4 >> 1, f_half = (f_f4 & 1) * 8;

    unsigned short* BhT = (unsigned short*)smB;
    unsigned short* BlT = (unsigned short*)(smB + 8192);

    f32x16 acc[2][2] = {};

    for (int k0 = 0; k0 < K; k0 += 32) {
        const int kb = k0 >> 3;
        if constexpr (AMODE == 1) {
            #pragma unroll
            for (int it = 0; it < 2; ++it) {
                int g = it * 256 + tid;
                int qq = g >> 7, r = g & 127;
                size_t src = ((size_t)(kb + qq) * M + m0 + r) * 8;
                gl_lds16(Agh + src, smA + g * 16);
                gl_lds16(Agl + src, smA + 8192 + g * 16);
            }
        } else if constexpr (AMODE == 2) {
            #pragma unroll
            for (int it = 0; it < 4; ++it) {
                int row = it * 32 + (tid >> 3);
                int slot = (tid & 7) ^ (row & 7);
                gl_lds16(Ap + (size_t)(m0 + row) * K + k0 + slot * 4,
                         smA + (size_t)(it * 256 + tid) * 16);
            }
        }
        if constexpr (BMODE == 1) {
            #pragma unroll
            for (int it = 0; it < 2; ++it) {
                int g = it * 256 + tid;
                int qq = g >> 7, r = g & 127;
                size_t src = ((size_t)(kb + qq) * N + n0 + r) * 8;
                gl_lds16(Bgh + src, smB + g * 16);
                gl_lds16(Bgl + src, smB + 8192 + g * 16);
            }
        } else if constexpr (BMODE == 2) {
            #pragma unroll
            for (int it = 0; it < 4; ++it) {
                int row = it * 32 + (tid >> 3);
                int slot = (tid & 7) ^ (row & 7);
                gl_lds16(Bp + (size_t)(n0 + row) * K + k0 + slot * 4,
                         smB + (size_t)(it * 256 + tid) * 16);
            }
        } else {
            #pragma unroll
            for (int it = 0; it < 4; ++it) {
                int r = it * 32 + f_r;
                float4 v = *(const float4*)&Bf[(size_t)(n0 + r) * K + k0 + f_f4 * 4];
                unsigned hb0 = bf16rn_bits(v.x), hb1 = bf16rn_bits(v.y);
                unsigned hb2 = bf16rn_bits(v.z), hb3 = bf16rn_bits(v.w);
                unsigned l0 = bf16rn_bits(v.x - __uint_as_float(hb0)) >> 16;
                unsigned l1 = bf16rn_bits(v.y - __uint_as_float(hb1)) >> 16;
                unsigned l2 = bf16rn_bits(v.z - __uint_as_float(hb2)) >> 16;
                unsigned l3 = bf16rn_bits(v.w - __uint_as_float(hb3)) >> 16;
                unsigned h0 = hb0 >> 16, h1 = hb1 >> 16, h2 = hb2 >> 16, h3 = hb3 >> 16;
                *(uint2*)((char*)(BhT + (f_qq * 128 + r) * 8) + f_half) =
                    make_uint2(h0 | (h1 << 16), h2 | (h3 << 16));
                *(uint2*)((char*)(BlT + (f_qq * 128 + r) * 8) + f_half) =
                    make_uint2(l0 | (l1 << 16), l2 | (l3 << 16));
            }
        }
        __syncthreads();

        short8 ah[2][2], al[2][2], bh[2][2], bl[2][2];
        #pragma unroll
        for (int mi = 0; mi < 2; ++mi) {
            int r = wm * 64 + mi * 32 + l31;
            #pragma unroll
            for (int ko = 0; ko < 2; ++ko) {
                int o = 2 * ko + lh;
                if constexpr (AMODE == 2) {
                    int s0 = (2 * o) ^ (r & 7), s1 = s0 ^ 1;
                    const unsigned* base = (const unsigned*)smA + r * 32;
                    uint4 a = *(const uint4*)(base + s0 * 4);
                    uint4 b = *(const uint4*)(base + s1 * 4);
                    unpack8(a, b, ah[mi][ko], al[mi][ko]);
                } else {
                    ah[mi][ko] = *(const short8*)((const unsigned short*)smA + (o * 128 + r) * 8);
                    al[mi][ko] = *(const short8*)((const unsigned short*)(smA + 8192) + (o * 128 + r) * 8);
                }
            }
        }
        #pragma unroll
        for (int ni = 0; ni < 2; ++ni) {
            int r = wn * 64 + ni * 32 + l31;
            #pragma unroll
            for (int ko = 0; ko < 2; ++ko) {
                int o = 2 * ko + lh;
                if constexpr (BMODE == 2) {
                    int s0 = (2 * o) ^ (r & 7), s1 = s0 ^ 1;
                    const unsigned* base = (const unsigned*)smB + r * 32;
                    uint4 a = *(const uint4*)(base + s0 * 4);
                    uint4 b = *(const uint4*)(base + s1 * 4);
                    unpack8(a, b, bh[ni][ko], bl[ni][ko]);
                } else {
                    bh[ni][ko] = *(const short8*)(BhT + (o * 128 + r) * 8);
                    bl[ni][ko] = *(const short8*)(BlT + (o * 128 + r) * 8);
                }
            }
        }
        #pragma unroll
        for (int ko = 0; ko < 2; ++ko)
            #pragma unroll
            for (int mi = 0; mi < 2; ++mi)
                #pragma unroll
                for (int ni = 0; ni < 2; ++ni) {
                    acc[mi][ni] = __builtin_amdgcn_mfma_f32_32x32x16_bf16(ah[mi][ko], bh[ni][ko], acc[mi][ni], 0, 0, 0);
                    acc[mi][ni] = __builtin_amdgcn_mfma_f32_32x32x16_bf16(ah[mi][ko], bl[ni][ko], acc[mi][ni], 0, 0, 0);
                    acc[mi][ni] = __builtin_amdgcn_mfma_f32_32x32x16_bf16(al[mi][ko], bh[ni][ko], acc[mi][ni], 0, 0, 0);
                }
        __syncthreads();
    }

    #pragma unroll
    for (int mi = 0; mi < 2; ++mi) {
        #pragma unroll
        for (int ni = 0; ni < 2; ++ni) {
            int gc = n0 + wn * 64 + ni * 32 + l31;
            #pragma unroll
            for (int reg = 0; reg < 16; ++reg) {
                int gr = m0 + wm * 64 + mi * 32 + (reg & 3) + 8 * (reg >> 2) + 4 * lh;
                float b = BIAS_ROW ? bias[gr] : bias[gc];
                float v = gelu_exact(acc[mi][ni][reg] + b);
                if constexpr (OUTF) outF[(size_t)gr * N + gc] = v;
                else                outP[(size_t)gr * N + gc] = packsplit(v);
            }
        }
    }
}

// ---------------------------------------------------------------------------
// MFMA attention: one wave per (window, head). R9: ALL block barriers removed
// — every LDS buffer is [wid]-private, and DS ops within a wave complete in
// order, so write->read ordering holds per-wave without __syncthreads.
// ---------------------------------------------------------------------------
__global__ __launch_bounds__(256, 2)
void attn_mfma(const unsigned* __restrict__ Tp, const float* __restrict__ bias_table,
               unsigned* __restrict__ Yp) {
    __shared__ unsigned short Vh[4][32][72];
    __shared__ unsigned short Vl[4][32][72];
    __shared__ unsigned PHs[4][16][36];
    __shared__ unsigned PLs[4][16][36];

    const int tid = threadIdx.x, wid = tid >> 6, lane = tid & 63;
    const int pidx = blockIdx.x * 4 + wid;
    const int b2 = pidx / NHEADS, h = pidx - b2 * NHEADS;
    const size_t qoff = (size_t)b2 * 18816 + (size_t)h * 1568;
    const int r15 = lane & 15, g = lane >> 4;

    #pragma unroll
    for (int it = 0; it < 8; ++it) {
        int idx = it * 64 + lane;
        int t = idx >> 3, dq = idx & 7;
        int tc = t > 48 ? 48 : t;
        uint4 w = *(const uint4*)&Tp[2 * QL + qoff + (size_t)tc * HD + dq * 4];
        #pragma unroll
        for (int c = 0; c < 4; ++c) {
            unsigned pw = (c == 0) ? w.x : (c == 1) ? w.y : (c == 2) ? w.z : w.w;
            Vh[wid][dq * 4 + c][t] = (unsigned short)(pw >> 16);
            Vl[wid][dq * 4 + c][t] = (unsigned short)(pw & 0xffffu);
        }
    }

    f32x4 S[4][4];
    int cS[4];
    #pragma unroll
    for (int st = 0; st < 4; ++st) {
        int s = st * 16 + r15; if (s > 48) s = 48;
        int sd = (s * 37) >> 8;
        cS[st] = 156 * (12 - (s - 6 * sd)) + h;
    }
    #pragma unroll
    for (int tt = 0; tt < 4; ++tt)
        #pragma unroll
        for (int r = 0; r < 4; ++r) {
            int t = tt * 16 + 4 * g + r; int tc2 = t > 48 ? 48 : t;
            int td = (tc2 * 37) >> 8;
            int at = 156 * (tc2 - 6 * td);
            #pragma unroll
            for (int st = 0; st < 4; ++st)
                S[tt][st][r] = bias_table[at + cS[st]];
        }

    short8 qh[4], qlo[4];
    #pragma unroll
    for (int st = 0; st < 4; ++st) {
        int s = st * 16 + r15; if (s > 48) s = 48;
        const unsigned* p = Tp + qoff + (size_t)s * HD + g * 8;
        uint4 a = *(const uint4*)p;
        uint4 b = *(const uint4*)(p + 4);
        unpack8(a, b, qh[st], qlo[st]);
    }
    #pragma unroll
    for (int tt = 0; tt < 4; ++tt) {
        int t = tt * 16 + r15; if (t > 48) t = 48;
        const unsigned* p = Tp + QL + qoff + (size_t)t * HD + g * 8;
        uint4 a = *(const uint4*)p;
        uint4 b = *(const uint4*)(p + 4);
        short8 kh, kl; unpack8(a, b, kh, kl);
        #pragma unroll
        for (int st = 0; st < 4; ++st) {
            S[tt][st] = __builtin_amdgcn_mfma_f32_16x16x32_bf16(kh, qh[st],  S[tt][st], 0, 0, 0);
            S[tt][st] = __builtin_amdgcn_mfma_f32_16x16x32_bf16(kh, qlo[st], S[tt][st], 0, 0, 0);
            S[tt][st] = __builtin_amdgcn_mfma_f32_16x16x32_bf16(kl, qh[st],  S[tt][st], 0, 0, 0);
        }
    }
    #pragma unroll
    for (int st = 0; st < 4; ++st) {
        S[3][st][0] = (g == 0) ? S[3][st][0] : -1e30f;
        S[3][st][1] = -1e30f; S[3][st][2] = -1e30f; S[3][st][3] = -1e30f;
    }
    float inv[4];
    #pragma unroll
    for (int st = 0; st < 4; ++st) {
        float mx = -1e30f;
        #pragma unroll
        for (int tt = 0; tt < 4; ++tt)
            #pragma unroll
            for (int r = 0; r < 4; ++r) mx = fmaxf(mx, S[tt][st][r]);
        mx = fmaxf(mx, __shfl_xor(mx, 16));
        mx = fmaxf(mx, __shfl_xor(mx, 32));
        float sm = 0.f;
        #pragma unroll
        for (int tt = 0; tt < 4; ++tt)
            #pragma unroll
            for (int r = 0; r < 4; ++r) {
                float e = __expf(S[tt][st][r] - mx);
                S[tt][st][r] = e; sm += e;
            }
        sm += __shfl_xor(sm, 16);
        sm += __shfl_xor(sm, 32);
        inv[st] = 1.0f / sm;
    }
    short8 vfh[2][2], vfl[2][2];
    #pragma unroll
    for (int dt = 0; dt < 2; ++dt)
        #pragma unroll
        for (int kc = 0; kc < 2; ++kc) {
            int d = dt * 16 + r15;
            vfh[dt][kc] = *(const short8*)&Vh[wid][d][kc * 32 + g * 8];
            vfl[dt][kc] = *(const short8*)&Vl[wid][d][kc * 32 + g * 8];
        }
    for (int st = 0; st < 4; ++st) {
        #pragma unroll
        for (int tt = 0; tt < 4; ++tt)
            #pragma unroll
            for (int rp = 0; rp < 2; ++rp) {
                float p0 = S[tt][st][2 * rp]     * inv[st];
                float p1 = S[tt][st][2 * rp + 1] * inv[st];
                unsigned h0 = bf16rn_bits(p0), h1 = bf16rn_bits(p1);
                unsigned l0 = bf16rn_bits(p0 - __uint_as_float(h0));
                unsigned l1 = bf16rn_bits(p1 - __uint_as_float(h1));
                int w = tt * 8 + 2 * g + rp;
                int wsw = (((w >> 2) ^ (r15 & 7)) << 2) + (w & 3);
                PHs[wid][r15][wsw] = __builtin_amdgcn_perm(h1, h0, 0x07060302u);
                PLs[wid][r15][wsw] = __builtin_amdgcn_perm(l1, l0, 0x05040100u ^ 0x02020202u);  // placeholder replaced below
            }
        // (the perm selector above for PLs must match PHs packing of lo words)
        #pragma unroll
        for (int tt = 0; tt < 4; ++tt)
            #pragma unroll
            for (int rp = 0; rp < 2; ++rp) {
                float p0 = S[tt][st][2 * rp]     * inv[st];
                float p1 = S[tt][st][2 * rp + 1] * inv[st];
                unsigned h0 = bf16rn_bits(p0), h1 = bf16rn_bits(p1);
                unsigned l0 = bf16rn_bits(p0 - __uint_as_float(h0));
                unsigned l1 = bf16rn_bits(p1 - __uint_as_float(h1));
                int w = tt * 8 + 2 * g + rp;
                int wsw = (((w >> 2) ^ (r15 & 7)) << 2) + (w & 3);
                PLs[wid][r15][wsw] = __builtin_amdgcn_perm(l1, l0, 0x07060302u);
            }
        f32x4 o[2] = {};
        #pragma unroll
        for (int kc = 0; kc < 2; ++kc) {
            int grp = (4 * kc + g) ^ (r15 & 7);
            short8 ph = *(const short8*)&PHs[wid][r15][grp * 4];
            short8 pl = *(const short8*)&PLs[wid][r15][grp * 4];
            #pragma unroll
            for (int dt = 0; dt < 2; ++dt) {
                o[dt] = __builtin_amdgcn_mfma_f32_16x16x32_bf16(ph, vfh[dt][kc], o[dt], 0, 0, 0);
                o[dt] = __builtin_amdgcn_mfma_f32_16x16x32_bf16(ph, vfl[dt][kc], o[dt], 0, 0, 0);
                o[dt] = __builtin_amdgcn_mfma_f32_16x16x32_bf16(pl, vfh[dt][kc], o[dt], 0, 0, 0);
            }
        }
        #pragma unroll
        for (int r = 0; r < 4; ++r) {
            int s = st * 16 + 4 * g + r;
            if (s < SEQ) {
                size_t ob = ((size_t)b2 * SEQ + s) * CDIM + h * HD + r15;
                Yp[ob]      = packsplit(o[0][r]);
                Yp[ob + 16] = packsplit(o[1][r]);
            }
        }
    }
}

extern "C" void kernel_launch(void* const* d_in, const int* in_sizes, int n_in,
                              void* d_out, int out_size, void* d_ws, size_t ws_size,
                              hipStream_t stream) {
    const float* x          = (const float*)d_in[0];
    const float* w_qkv      = (const float*)d_in[1];
    const float* b_qkv      = (const float*)d_in[2];
    const float* bias_table = (const float*)d_in[3];
    const float* w_out      = (const float*)d_in[4];
    const float* b_out      = (const float*)d_in[5];
    unsigned* Tp = (unsigned*)d_ws;
    const size_t TPW = 3 * QL;

    const size_t need = TPW * 4ULL + (size_t)NH3 * CDIM * 4ULL + (size_t)CDIM * CDIM * 4ULL;

    if (ws_size >= need) {
        unsigned short* wq_hi = (unsigned short*)((char*)d_ws + TPW * 4ULL);
        unsigned short* wq_lo = wq_hi + (size_t)NH3 * CDIM;
        unsigned short* wo_hi = wq_lo + (size_t)NH3 * CDIM;
        unsigned short* wo_lo = wo_hi + (size_t)CDIM * CDIM;
        unsigned* xp = (unsigned*)d_out;

        prep_w<<<(NH3 * 48 + 255) / 256, 256, 0, stream>>>(w_qkv, wq_hi, wq_lo, NH3, CDIM);
        prep_w<<<(CDIM * 48 + 255) / 256, 256, 0, stream>>>(w_out, wo_hi, wo_lo, CDIM, CDIM);
        prep_x<<<(NTOK * CDIM / 8 + 255) / 256, 256, 0, stream>>>(x, xp, NTOK * CDIM / 8);

        gemm_b3<1, 2, true, false><<<14112, 256, 0, stream>>>(
            nullptr, wq_hi, wq_lo, nullptr, nullptr, nullptr, nullptr, xp,
            b_qkv, nullptr, Tp, NH3, NTOK, CDIM, 9, 1764);

        attn_mfma<<<12288, 256, 0, stream>>>(Tp, bias_table, (unsigned*)d_out);

        gemm_b3<2, 1, false, false><<<dim3(3, 1568), 256, 0, stream>>>(
            nullptr, nullptr, nullptr, (unsigned*)d_out, nullptr, wo_hi, wo_lo, nullptr,
            b_out, nullptr, Tp, NTOK, CDIM, CDIM, 0, 0);

        gemm_b3<2, 1, false, true><<<dim3(3, 1568), 256, 0, stream>>>(
            nullptr, nullptr, nullptr, Tp, nullptr, wo_hi, wo_lo, nullptr,
            b_out, (float*)d_out, nullptr, NTOK, CDIM, CDIM, 0, 0);
    } else {
        // fallback: weights in d_out / dead T third; x staged fp32 inline
        unsigned short* wq_hi = (unsigned short*)d_out;
        unsigned short* wq_lo = wq_hi + (size_t)NH3 * CDIM;
        unsigned short* wo_hi = (unsigned short*)(Tp + QL);
        unsigned short* wo_lo = wo_hi + (size_t)CDIM * CDIM;

        prep_w<<<(NH3 * 48 + 255) / 256, 256, 0, stream>>>(w_qkv, wq_hi, wq_lo, NH3, CDIM);

        gemm_b3<1, 0, true, false><<<14112, 256, 0, stream>>>(
            nullptr, wq_hi, wq_lo, nullptr, x, nullptr, nullptr, nullptr,
            b_qkv, nullptr, Tp, NH3, NTOK, CDIM, 9, 1764);

        attn_mfma<<<12288, 256, 0, stream>>>(Tp, bias_table, (unsigned*)d_out);

        prep_w<<<(CDIM * 48 + 255) / 256, 256, 0, stream>>>(w_out, wo_hi, wo_lo, CDIM, CDIM);

        gemm_b3<2, 1, false, false><<<dim3(3, 1568), 256, 0, stream>>>(
            nullptr, nullptr, nullptr, (unsigned*)d_out, nullptr, wo_hi, wo_lo, nullptr,
            b_out, nullptr, Tp, NTOK, CDIM, CDIM, 0, 0);

        gemm_b3<2, 1, false, true><<<dim3(3, 1568), 256, 0, stream>>>(
            nullptr, nullptr, nullptr, Tp, nullptr, wo_hi, wo_lo, nullptr,
            b_out, (float*)d_out, nullptr, NTOK, CDIM, CDIM, 0, 0);
    }
}

// Round 10
// 1518.224 us; speedup vs baseline: 1.2690x; 1.0235x over previous
//
#include <hip/hip_runtime.h>
#include <math.h>

#define NTOK 200704          // B*S = 4096*49
#define CDIM 384
#define NH3  1152            // 3*C
#define NHEADS 12
#define HD   32
#define SEQ  49
#define QL   77070336ULL     // CDIM*NTOK (one third of T)

typedef __attribute__((ext_vector_type(8))) short short8;
typedef __attribute__((ext_vector_type(4))) float f32x4;
typedef __attribute__((ext_vector_type(16))) float f32x16;

__device__ __forceinline__ float gelu_exact(float x) {
    return 0.5f * x * (1.0f + erff(x * 0.70710678118654752f));
}
__device__ __forceinline__ unsigned bf16rn_bits(float x) {
    unsigned u = __float_as_uint(x);
    return (u + 0x7fffu + ((u >> 16) & 1u)) & 0xffff0000u;
}
__device__ __forceinline__ unsigned packsplit(float x) {
    unsigned hb = bf16rn_bits(x);
    float r = x - __uint_as_float(hb);
    unsigned lb = bf16rn_bits(r);
    return hb | (lb >> 16);
}
__device__ __forceinline__ void gl_lds16(const void* g, void* l) {
    __builtin_amdgcn_global_load_lds((const __attribute__((address_space(1))) void*)g,
                                     (__attribute__((address_space(3))) void*)l, 16, 0, 0);
}
union F8 { short8 v; unsigned u[4]; };
__device__ __forceinline__ void unpack8(uint4 a, uint4 b, short8 &h, short8 &l) {
    F8 H, L;
    H.u[0] = __builtin_amdgcn_perm(a.y, a.x, 0x07060302u);
    H.u[1] = __builtin_amdgcn_perm(a.w, a.z, 0x07060302u);
    H.u[2] = __builtin_amdgcn_perm(b.y, b.x, 0x07060302u);
    H.u[3] = __builtin_amdgcn_perm(b.w, b.z, 0x07060302u);
    L.u[0] = __builtin_amdgcn_perm(a.y, a.x, 0x05040100u);
    L.u[1] = __builtin_amdgcn_perm(a.w, a.z, 0x05040100u);
    L.u[2] = __builtin_amdgcn_perm(b.y, b.x, 0x05040100u);
    L.u[3] = __builtin_amdgcn_perm(b.w, b.z, 0x05040100u);
    h = H.v; l = L.v;
}

// ---------------------------------------------------------------------------
// prep_w: w (Kdim x Mdim row-major fp32) -> hi/lo bf16 granules [koct][Mdim][8]
// ---------------------------------------------------------------------------
__global__ __launch_bounds__(256)
void prep_w(const float* __restrict__ w, unsigned short* __restrict__ hi,
            unsigned short* __restrict__ lo, int Mdim, int Kdim) {
    int idx = blockIdx.x * 256 + threadIdx.x;
    int total = Mdim * (Kdim >> 3);
    if (idx >= total) return;
    int koct = idx / Mdim, m = idx - koct * Mdim;
    unsigned short h8[8], l8[8];
    #pragma unroll
    for (int j = 0; j < 8; ++j) {
        float v = w[(size_t)(koct * 8 + j) * Mdim + m];
        unsigned hb = bf16rn_bits(v);
        h8[j] = (unsigned short)(hb >> 16);
        l8[j] = (unsigned short)(bf16rn_bits(v - __uint_as_float(hb)) >> 16);
    }
    size_t o = (size_t)idx * 8;
    *(short8*)&hi[o] = *(short8*)h8;
    *(short8*)&lo[o] = *(short8*)l8;
}

// prep_x: fp32 row-major -> packed-split u32, same layout
__global__ __launch_bounds__(256)
void prep_x(const float* __restrict__ x, unsigned* __restrict__ xp, int total8) {
    int idx = blockIdx.x * 256 + threadIdx.x;
    if (idx >= total8) return;
    size_t e = (size_t)idx * 8;
    float4 v0 = *(const float4*)&x[e];
    float4 v1 = *(const float4*)&x[e + 4];
    *(uint4*)&xp[e]     = make_uint4(packsplit(v0.x), packsplit(v0.y), packsplit(v0.z), packsplit(v0.w));
    *(uint4*)&xp[e + 4] = make_uint4(packsplit(v1.x), packsplit(v1.y), packsplit(v1.z), packsplit(v1.w));
}

// ---------------------------------------------------------------------------
// bf16x3 GEMM, 128x128 tile, BK=32, 4 waves (2x2 of 64x64), single-buffered
// LDS, MFMA 32x32x16. (unchanged from R9)
// ---------------------------------------------------------------------------
template<int AMODE, int BMODE, bool BIAS_ROW, bool OUTF>
__global__ __launch_bounds__(256, 4)
void gemm_b3(const float* __restrict__ Af,
             const unsigned short* __restrict__ Agh, const unsigned short* __restrict__ Agl,
             const unsigned* __restrict__ Ap,
             const float* __restrict__ Bf,
             const unsigned short* __restrict__ Bgh, const unsigned short* __restrict__ Bgl,
             const unsigned* __restrict__ Bp,
             const float* __restrict__ bias, float* __restrict__ outF,
             unsigned* __restrict__ outP,
             int M, int N, int K, int nMt, int cpx) {
    __shared__ char smA[16384];
    __shared__ char smB[16384];
    const int tid = threadIdx.x;
    int m0, n0;
    if (cpx > 0) {  // XCD-chunked 1D grid: consecutive wg share the token tile
        int wg = (blockIdx.x & 7) * cpx + (blockIdx.x >> 3);
        m0 = (wg % nMt) * 128;
        n0 = (wg / nMt) * 128;
    } else {
        n0 = blockIdx.x * 128;
        m0 = blockIdx.y * 128;
    }
    const int wid = tid >> 6, lane = tid & 63;
    const int wm = wid >> 1, wn = wid & 1;
    const int l31 = lane & 31, lh = lane >> 5;
    const int f_r = tid >> 3, f_f4 = tid & 7;
    const int f_qq = f_f4 >> 1, f_half = (f_f4 & 1) * 8;

    unsigned short* BhT = (unsigned short*)smB;
    unsigned short* BlT = (unsigned short*)(smB + 8192);

    f32x16 acc[2][2] = {};

    for (int k0 = 0; k0 < K; k0 += 32) {
        const int kb = k0 >> 3;
        if constexpr (AMODE == 1) {
            #pragma unroll
            for (int it = 0; it < 2; ++it) {
                int g = it * 256 + tid;
                int qq = g >> 7, r = g & 127;
                size_t src = ((size_t)(kb + qq) * M + m0 + r) * 8;
                gl_lds16(Agh + src, smA + g * 16);
                gl_lds16(Agl + src, smA + 8192 + g * 16);
            }
        } else if constexpr (AMODE == 2) {
            #pragma unroll
            for (int it = 0; it < 4; ++it) {
                int row = it * 32 + (tid >> 3);
                int slot = (tid & 7) ^ (row & 7);
                gl_lds16(Ap + (size_t)(m0 + row) * K + k0 + slot * 4,
                         smA + (size_t)(it * 256 + tid) * 16);
            }
        }
        if constexpr (BMODE == 1) {
            #pragma unroll
            for (int it = 0; it < 2; ++it) {
                int g = it * 256 + tid;
                int qq = g >> 7, r = g & 127;
                size_t src = ((size_t)(kb + qq) * N + n0 + r) * 8;
                gl_lds16(Bgh + src, smB + g * 16);
                gl_lds16(Bgl + src, smB + 8192 + g * 16);
            }
        } else if constexpr (BMODE == 2) {
            #pragma unroll
            for (int it = 0; it < 4; ++it) {
                int row = it * 32 + (tid >> 3);
                int slot = (tid & 7) ^ (row & 7);
                gl_lds16(Bp + (size_t)(n0 + row) * K + k0 + slot * 4,
                         smB + (size_t)(it * 256 + tid) * 16);
            }
        } else {
            #pragma unroll
            for (int it = 0; it < 4; ++it) {
                int r = it * 32 + f_r;
                float4 v = *(const float4*)&Bf[(size_t)(n0 + r) * K + k0 + f_f4 * 4];
                unsigned hb0 = bf16rn_bits(v.x), hb1 = bf16rn_bits(v.y);
                unsigned hb2 = bf16rn_bits(v.z), hb3 = bf16rn_bits(v.w);
                unsigned l0 = bf16rn_bits(v.x - __uint_as_float(hb0)) >> 16;
                unsigned l1 = bf16rn_bits(v.y - __uint_as_float(hb1)) >> 16;
                unsigned l2 = bf16rn_bits(v.z - __uint_as_float(hb2)) >> 16;
                unsigned l3 = bf16rn_bits(v.w - __uint_as_float(hb3)) >> 16;
                unsigned h0 = hb0 >> 16, h1 = hb1 >> 16, h2 = hb2 >> 16, h3 = hb3 >> 16;
                *(uint2*)((char*)(BhT + (f_qq * 128 + r) * 8) + f_half) =
                    make_uint2(h0 | (h1 << 16), h2 | (h3 << 16));
                *(uint2*)((char*)(BlT + (f_qq * 128 + r) * 8) + f_half) =
                    make_uint2(l0 | (l1 << 16), l2 | (l3 << 16));
            }
        }
        __syncthreads();

        short8 ah[2][2], al[2][2], bh[2][2], bl[2][2];
        #pragma unroll
        for (int mi = 0; mi < 2; ++mi) {
            int r = wm * 64 + mi * 32 + l31;
            #pragma unroll
            for (int ko = 0; ko < 2; ++ko) {
                int o = 2 * ko + lh;
                if constexpr (AMODE == 2) {
                    int s0 = (2 * o) ^ (r & 7), s1 = s0 ^ 1;
                    const unsigned* base = (const unsigned*)smA + r * 32;
                    uint4 a = *(const uint4*)(base + s0 * 4);
                    uint4 b = *(const uint4*)(base + s1 * 4);
                    unpack8(a, b, ah[mi][ko], al[mi][ko]);
                } else {
                    ah[mi][ko] = *(const short8*)((const unsigned short*)smA + (o * 128 + r) * 8);
                    al[mi][ko] = *(const short8*)((const unsigned short*)(smA + 8192) + (o * 128 + r) * 8);
                }
            }
        }
        #pragma unroll
        for (int ni = 0; ni < 2; ++ni) {
            int r = wn * 64 + ni * 32 + l31;
            #pragma unroll
            for (int ko = 0; ko < 2; ++ko) {
                int o = 2 * ko + lh;
                if constexpr (BMODE == 2) {
                    int s0 = (2 * o) ^ (r & 7), s1 = s0 ^ 1;
                    const unsigned* base = (const unsigned*)smB + r * 32;
                    uint4 a = *(const uint4*)(base + s0 * 4);
                    uint4 b = *(const uint4*)(base + s1 * 4);
                    unpack8(a, b, bh[ni][ko], bl[ni][ko]);
                } else {
                    bh[ni][ko] = *(const short8*)(BhT + (o * 128 + r) * 8);
                    bl[ni][ko] = *(const short8*)(BlT + (o * 128 + r) * 8);
                }
            }
        }
        #pragma unroll
        for (int ko = 0; ko < 2; ++ko)
            #pragma unroll
            for (int mi = 0; mi < 2; ++mi)
                #pragma unroll
                for (int ni = 0; ni < 2; ++ni) {
                    acc[mi][ni] = __builtin_amdgcn_mfma_f32_32x32x16_bf16(ah[mi][ko], bh[ni][ko], acc[mi][ni], 0, 0, 0);
                    acc[mi][ni] = __builtin_amdgcn_mfma_f32_32x32x16_bf16(ah[mi][ko], bl[ni][ko], acc[mi][ni], 0, 0, 0);
                    acc[mi][ni] = __builtin_amdgcn_mfma_f32_32x32x16_bf16(al[mi][ko], bh[ni][ko], acc[mi][ni], 0, 0, 0);
                }
        __syncthreads();
    }

    #pragma unroll
    for (int mi = 0; mi < 2; ++mi) {
        #pragma unroll
        for (int ni = 0; ni < 2; ++ni) {
            int gc = n0 + wn * 64 + ni * 32 + l31;
            #pragma unroll
            for (int reg = 0; reg < 16; ++reg) {
                int gr = m0 + wm * 64 + mi * 32 + (reg & 3) + 8 * (reg >> 2) + 4 * lh;
                float b = BIAS_ROW ? bias[gr] : bias[gc];
                float v = gelu_exact(acc[mi][ni][reg] + b);
                if constexpr (OUTF) outF[(size_t)gr * N + gc] = v;
                else                outP[(size_t)gr * N + gc] = packsplit(v);
            }
        }
    }
}

// ---------------------------------------------------------------------------
// MFMA attention: one wave per (window, head). No block barriers (all LDS
// is wave-private). R10: V^T staging via ds_write_b64 (16 DS ops/thread
// instead of 64 b16); duplicate PLs loop removed.
// ---------------------------------------------------------------------------
__global__ __launch_bounds__(256, 2)
void attn_mfma(const unsigned* __restrict__ Tp, const float* __restrict__ bias_table,
               unsigned* __restrict__ Yp) {
    __shared__ unsigned short Vh[4][32][72];
    __shared__ unsigned short Vl[4][32][72];
    __shared__ unsigned PHs[4][16][36];
    __shared__ unsigned PLs[4][16][36];

    const int tid = threadIdx.x, wid = tid >> 6, lane = tid & 63;
    const int pidx = blockIdx.x * 4 + wid;
    const int b2 = pidx / NHEADS, h = pidx - b2 * NHEADS;
    const size_t qoff = (size_t)b2 * 18816 + (size_t)h * 1568;
    const int r15 = lane & 15, g = lane >> 4;

    // ---- stage V^T: thread owns (dq = lane&7, tq = lane>>3 [+8]) ----
    // writes Vh/Vl[d = dq*4+c][t = tq*4 .. +3] as one b64 each.
    #pragma unroll
    for (int it = 0; it < 2; ++it) {
        const int dq = lane & 7;
        const int tq = (lane >> 3) + it * 8;
        uint4 p[4];
        #pragma unroll
        for (int u = 0; u < 4; ++u) {
            int t = tq * 4 + u; if (t > 48) t = 48;
            p[u] = *(const uint4*)&Tp[2 * QL + qoff + (size_t)t * HD + dq * 4];
        }
        #pragma unroll
        for (int c = 0; c < 4; ++c) {
            unsigned q0 = (c == 0) ? p[0].x : (c == 1) ? p[0].y : (c == 2) ? p[0].z : p[0].w;
            unsigned q1 = (c == 0) ? p[1].x : (c == 1) ? p[1].y : (c == 2) ? p[1].z : p[1].w;
            unsigned q2 = (c == 0) ? p[2].x : (c == 1) ? p[2].y : (c == 2) ? p[2].z : p[2].w;
            unsigned q3 = (c == 0) ? p[3].x : (c == 1) ? p[3].y : (c == 2) ? p[3].z : p[3].w;
            unsigned hw0 = __builtin_amdgcn_perm(q1, q0, 0x07060302u);
            unsigned hw1 = __builtin_amdgcn_perm(q3, q2, 0x07060302u);
            unsigned lw0 = __builtin_amdgcn_perm(q1, q0, 0x05040100u);
            unsigned lw1 = __builtin_amdgcn_perm(q3, q2, 0x05040100u);
            *(uint2*)&Vh[wid][dq * 4 + c][tq * 4] = make_uint2(hw0, hw1);
            *(uint2*)&Vl[wid][dq * 4 + c][tq * 4] = make_uint2(lw0, lw1);
        }
    }

    f32x4 S[4][4];
    int cS[4];
    #pragma unroll
    for (int st = 0; st < 4; ++st) {
        int s = st * 16 + r15; if (s > 48) s = 48;
        int sd = (s * 37) >> 8;
        cS[st] = 156 * (12 - (s - 6 * sd)) + h;
    }
    #pragma unroll
    for (int tt = 0; tt < 4; ++tt)
        #pragma unroll
        for (int r = 0; r < 4; ++r) {
            int t = tt * 16 + 4 * g + r; int tc2 = t > 48 ? 48 : t;
            int td = (tc2 * 37) >> 8;
            int at = 156 * (tc2 - 6 * td);
            #pragma unroll
            for (int st = 0; st < 4; ++st)
                S[tt][st][r] = bias_table[at + cS[st]];
        }

    short8 qh[4], qlo[4];
    #pragma unroll
    for (int st = 0; st < 4; ++st) {
        int s = st * 16 + r15; if (s > 48) s = 48;
        const unsigned* p = Tp + qoff + (size_t)s * HD + g * 8;
        uint4 a = *(const uint4*)p;
        uint4 b = *(const uint4*)(p + 4);
        unpack8(a, b, qh[st], qlo[st]);
    }
    #pragma unroll
    for (int tt = 0; tt < 4; ++tt) {
        int t = tt * 16 + r15; if (t > 48) t = 48;
        const unsigned* p = Tp + QL + qoff + (size_t)t * HD + g * 8;
        uint4 a = *(const uint4*)p;
        uint4 b = *(const uint4*)(p + 4);
        short8 kh, kl; unpack8(a, b, kh, kl);
        #pragma unroll
        for (int st = 0; st < 4; ++st) {
            S[tt][st] = __builtin_amdgcn_mfma_f32_16x16x32_bf16(kh, qh[st],  S[tt][st], 0, 0, 0);
            S[tt][st] = __builtin_amdgcn_mfma_f32_16x16x32_bf16(kh, qlo[st], S[tt][st], 0, 0, 0);
            S[tt][st] = __builtin_amdgcn_mfma_f32_16x16x32_bf16(kl, qh[st],  S[tt][st], 0, 0, 0);
        }
    }
    #pragma unroll
    for (int st = 0; st < 4; ++st) {
        S[3][st][0] = (g == 0) ? S[3][st][0] : -1e30f;
        S[3][st][1] = -1e30f; S[3][st][2] = -1e30f; S[3][st][3] = -1e30f;
    }
    float inv[4];
    #pragma unroll
    for (int st = 0; st < 4; ++st) {
        float mx = -1e30f;
        #pragma unroll
        for (int tt = 0; tt < 4; ++tt)
            #pragma unroll
            for (int r = 0; r < 4; ++r) mx = fmaxf(mx, S[tt][st][r]);
        mx = fmaxf(mx, __shfl_xor(mx, 16));
        mx = fmaxf(mx, __shfl_xor(mx, 32));
        float sm = 0.f;
        #pragma unroll
        for (int tt = 0; tt < 4; ++tt)
            #pragma unroll
            for (int r = 0; r < 4; ++r) {
                float e = __expf(S[tt][st][r] - mx);
                S[tt][st][r] = e; sm += e;
            }
        sm += __shfl_xor(sm, 16);
        sm += __shfl_xor(sm, 32);
        inv[st] = 1.0f / sm;
    }
    short8 vfh[2][2], vfl[2][2];
    #pragma unroll
    for (int dt = 0; dt < 2; ++dt)
        #pragma unroll
        for (int kc = 0; kc < 2; ++kc) {
            int d = dt * 16 + r15;
            vfh[dt][kc] = *(const short8*)&Vh[wid][d][kc * 32 + g * 8];
            vfl[dt][kc] = *(const short8*)&Vl[wid][d][kc * 32 + g * 8];
        }
    for (int st = 0; st < 4; ++st) {
        #pragma unroll
        for (int tt = 0; tt < 4; ++tt)
            #pragma unroll
            for (int rp = 0; rp < 2; ++rp) {
                float p0 = S[tt][st][2 * rp]     * inv[st];
                float p1 = S[tt][st][2 * rp + 1] * inv[st];
                unsigned h0 = bf16rn_bits(p0), h1 = bf16rn_bits(p1);
                unsigned l0 = bf16rn_bits(p0 - __uint_as_float(h0));
                unsigned l1 = bf16rn_bits(p1 - __uint_as_float(h1));
                int w = tt * 8 + 2 * g + rp;
                int wsw = (((w >> 2) ^ (r15 & 7)) << 2) + (w & 3);
                PHs[wid][r15][wsw] = __builtin_amdgcn_perm(h1, h0, 0x07060302u);
                PLs[wid][r15][wsw] = __builtin_amdgcn_perm(l1, l0, 0x07060302u);
            }
        f32x4 o[2] = {};
        #pragma unroll
        for (int kc = 0; kc < 2; ++kc) {
            int grp = (4 * kc + g) ^ (r15 & 7);
            short8 ph = *(const short8*)&PHs[wid][r15][grp * 4];
            short8 pl = *(const short8*)&PLs[wid][r15][grp * 4];
            #pragma unroll
            for (int dt = 0; dt < 2; ++dt) {
                o[dt] = __builtin_amdgcn_mfma_f32_16x16x32_bf16(ph, vfh[dt][kc], o[dt], 0, 0, 0);
                o[dt] = __builtin_amdgcn_mfma_f32_16x16x32_bf16(ph, vfl[dt][kc], o[dt], 0, 0, 0);
                o[dt] = __builtin_amdgcn_mfma_f32_16x16x32_bf16(pl, vfh[dt][kc], o[dt], 0, 0, 0);
            }
        }
        #pragma unroll
        for (int r = 0; r < 4; ++r) {
            int s = st * 16 + 4 * g + r;
            if (s < SEQ) {
                size_t ob = ((size_t)b2 * SEQ + s) * CDIM + h * HD + r15;
                Yp[ob]      = packsplit(o[0][r]);
                Yp[ob + 16] = packsplit(o[1][r]);
            }
        }
    }
}

extern "C" void kernel_launch(void* const* d_in, const int* in_sizes, int n_in,
                              void* d_out, int out_size, void* d_ws, size_t ws_size,
                              hipStream_t stream) {
    const float* x          = (const float*)d_in[0];
    const float* w_qkv      = (const float*)d_in[1];
    const float* b_qkv      = (const float*)d_in[2];
    const float* bias_table = (const float*)d_in[3];
    const float* w_out      = (const float*)d_in[4];
    const float* b_out      = (const float*)d_in[5];
    unsigned* Tp = (unsigned*)d_ws;
    const size_t TPW = 3 * QL;

    const size_t need = TPW * 4ULL + (size_t)NH3 * CDIM * 4ULL + (size_t)CDIM * CDIM * 4ULL;

    if (ws_size >= need) {
        unsigned short* wq_hi = (unsigned short*)((char*)d_ws + TPW * 4ULL);
        unsigned short* wq_lo = wq_hi + (size_t)NH3 * CDIM;
        unsigned short* wo_hi = wq_lo + (size_t)NH3 * CDIM;
        unsigned short* wo_lo = wo_hi + (size_t)CDIM * CDIM;
        unsigned* xp = (unsigned*)d_out;

        prep_w<<<(NH3 * 48 + 255) / 256, 256, 0, stream>>>(w_qkv, wq_hi, wq_lo, NH3, CDIM);
        prep_w<<<(CDIM * 48 + 255) / 256, 256, 0, stream>>>(w_out, wo_hi, wo_lo, CDIM, CDIM);
        prep_x<<<(NTOK * CDIM / 8 + 255) / 256, 256, 0, stream>>>(x, xp, NTOK * CDIM / 8);

        gemm_b3<1, 2, true, false><<<14112, 256, 0, stream>>>(
            nullptr, wq_hi, wq_lo, nullptr, nullptr, nullptr, nullptr, xp,
            b_qkv, nullptr, Tp, NH3, NTOK, CDIM, 9, 1764);

        attn_mfma<<<12288, 256, 0, stream>>>(Tp, bias_table, (unsigned*)d_out);

        gemm_b3<2, 1, false, false><<<dim3(3, 1568), 256, 0, stream>>>(
            nullptr, nullptr, nullptr, (unsigned*)d_out, nullptr, wo_hi, wo_lo, nullptr,
            b_out, nullptr, Tp, NTOK, CDIM, CDIM, 0, 0);

        gemm_b3<2, 1, false, true><<<dim3(3, 1568), 256, 0, stream>>>(
            nullptr, nullptr, nullptr, Tp, nullptr, wo_hi, wo_lo, nullptr,
            b_out, (float*)d_out, nullptr, NTOK, CDIM, CDIM, 0, 0);
    } else {
        // fallback: weights in d_out / dead T third; x staged fp32 inline
        unsigned short* wq_hi = (unsigned short*)d_out;
        unsigned short* wq_lo = wq_hi + (size_t)NH3 * CDIM;
        unsigned short* wo_hi = (unsigned short*)(Tp + QL);
        unsigned short* wo_lo = wo_hi + (size_t)CDIM * CDIM;

        prep_w<<<(NH3 * 48 + 255) / 256, 256, 0, stream>>>(w_qkv, wq_hi, wq_lo, NH3, CDIM);

        gemm_b3<1, 0, true, false><<<14112, 256, 0, stream>>>(
            nullptr, wq_hi, wq_lo, nullptr, x, nullptr, nullptr, nullptr,
            b_qkv, nullptr, Tp, NH3, NTOK, CDIM, 9, 1764);

        attn_mfma<<<12288, 256, 0, stream>>>(Tp, bias_table, (unsigned*)d_out);

        prep_w<<<(CDIM * 48 + 255) / 256, 256, 0, stream>>>(w_out, wo_hi, wo_lo, CDIM, CDIM);

        gemm_b3<2, 1, false, false><<<dim3(3, 1568), 256, 0, stream>>>(
            nullptr, nullptr, nullptr, (unsigned*)d_out, nullptr, wo_hi, wo_lo, nullptr,
            b_out, nullptr, Tp, NTOK, CDIM, CDIM, 0, 0);

        gemm_b3<2, 1, false, true><<<dim3(3, 1568), 256, 0, stream>>>(
            nullptr, nullptr, nullptr, Tp, nullptr, wo_hi, wo_lo, nullptr,
            b_out, (float*)d_out, nullptr, NTOK, CDIM, CDIM, 0, 0);
    }
}